// Round 3
// baseline (644.995 us; speedup 1.0000x reference)
//
#include <hip/hip_runtime.h>

#define D 128
#define NG 64

typedef unsigned short ushort_t;
typedef unsigned int uint_t;

__device__ __forceinline__ float bflo(uint_t w) { return __uint_as_float(w << 16); }
__device__ __forceinline__ float bfhi(uint_t w) { return __uint_as_float(w & 0xFFFF0000u); }
__device__ __forceinline__ float bf2f(ushort_t u) { return __uint_as_float(((uint_t)u) << 16); }
__device__ __forceinline__ ushort_t f2bf(float f) {
  uint_t x = __float_as_uint(f);
  x = x + 0x7FFFu + ((x >> 16) & 1u);
  return (ushort_t)(x >> 16);
}

// ---- converted-parameter element offsets (f32 scratch) ----
static constexpr int OW1 = 0, OB1 = 16384, OW2 = 16512, OB2 = 32896, OW3 = 33024,
                     OB3 = 49408, OFW1 = 49536, OFB1 = 57728, OFW2 = 57792,
                     OFB2 = 59840, OFW3 = 59872, OFB3 = 59904, WTOT = 59905;

// ---------------- dtype detection ----------------
// If float data is stored f32 and decoded as bf16 halves, low halves are ~random
// 16-bit patterns: many decode to |v|>1e6 or exp=0xFF. If stored bf16 (~N(0,1)),
// none do. flag=1 -> bf16 storage, flag=0 -> f32 storage.
__global__ void detect_kernel(const ushort_t* __restrict__ x, int* __restrict__ flag) {
  __shared__ int bad;
  if (threadIdx.x == 0) bad = 0;
  __syncthreads();
  int b = 0;
  for (int i = threadIdx.x; i < 4096; i += 256) {
    ushort_t u = x[i];
    int e = (u >> 7) & 0xFF;
    float v = bf2f(u);
    if (e == 0xFF || fabsf(v) > 1e6f) b++;
  }
  if (b) atomicAdd(&bad, b);
  __syncthreads();
  if (threadIdx.x == 0) *flag = (bad == 0) ? 1 : 0;
}

// ---------------- convert all params to f32 scratch ----------------
__global__ __launch_bounds__(256) void convert_params(
    const void* W1, const void* b1, const void* W2, const void* b2,
    const void* W3, const void* b3, const void* fw1, const void* fb1,
    const void* fw2, const void* fb2, const void* fw3, const void* fb3,
    const int* __restrict__ flag, float* __restrict__ out) {
  int i = blockIdx.x * 256 + threadIdx.x;
  if (i >= WTOT) return;
  const void* src; int local;
  if      (i < OB1)  { src = W1;  local = i; }
  else if (i < OW2)  { src = b1;  local = i - OB1; }
  else if (i < OB2)  { src = W2;  local = i - OW2; }
  else if (i < OW3)  { src = b2;  local = i - OB2; }
  else if (i < OB3)  { src = W3;  local = i - OW3; }
  else if (i < OFW1) { src = b3;  local = i - OB3; }
  else if (i < OFB1) { src = fw1; local = i - OFW1; }
  else if (i < OFW2) { src = fb1; local = i - OFB1; }
  else if (i < OFB2) { src = fw2; local = i - OFW2; }
  else if (i < OFW3) { src = fb2; local = i - OFB2; }
  else if (i < OFB3) { src = fw3; local = i - OFW3; }
  else               { src = fb3; local = i - OFB3; }
  bool bf = (*flag != 0);
  out[i] = bf ? bf2f(((const ushort_t*)src)[local]) : ((const float*)src)[local];
}

// ---------------- CSR build ----------------
__global__ void deg_kernel(const int* __restrict__ ei, int* __restrict__ deg, int E) {
  int e = blockIdx.x * 256 + threadIdx.x;
  if (e < E) atomicAdd(&deg[ei[E + e]], 1);
}

__global__ void dinv_kernel(const int* __restrict__ deg, float* __restrict__ dinv, int n) {
  int i = blockIdx.x * 256 + threadIdx.x;
  if (i < n) dinv[i] = rsqrtf((float)(deg[i] + 1));  // +1 self loop
}

__global__ __launch_bounds__(1024) void scan_kernel(const int* __restrict__ deg,
                                                    int* __restrict__ row,
                                                    int* __restrict__ cur, int n) {
  __shared__ int partial[1024];
  const int tid = threadIdx.x;
  const int chunk = (n + 1023) / 1024;
  const int lo = min(tid * chunk, n);
  const int hi = min(lo + chunk, n);
  int s = 0;
  for (int i = lo; i < hi; i++) s += deg[i];
  partial[tid] = s;
  __syncthreads();
  for (int off = 1; off < 1024; off <<= 1) {
    int v = (tid >= off) ? partial[tid - off] : 0;
    __syncthreads();
    partial[tid] += v;
    __syncthreads();
  }
  int base = (tid == 0) ? 0 : partial[tid - 1];
  for (int i = lo; i < hi; i++) {
    row[i] = base; cur[i] = base;
    base += deg[i];
  }
  if (tid == 1023) row[n] = partial[1023];
}

__global__ void fill_kernel(const int* __restrict__ ei, int* __restrict__ cur,
                            int* __restrict__ csr, int E) {
  int e = blockIdx.x * 256 + threadIdx.x;
  if (e < E) {
    int src = ei[e];
    int dst = ei[E + e];
    int pos = atomicAdd(&cur[dst], 1);
    csr[pos] = src;
  }
}

// ---------------- GEMM: out[n][128](bf16) = in[n][128] @ Wf[128][128](f32) ----------------
__global__ __launch_bounds__(256) void gemm128(const void* __restrict__ Ain,
                                               const float* __restrict__ Wf,
                                               ushort_t* __restrict__ out, int n,
                                               const int* __restrict__ flag,
                                               int src_is_input) {
  __shared__ float lin[64 * 132];
  const int tid = threadIdx.x;
  const int r0 = blockIdx.x * 64;
  const bool bf = src_is_input ? (*flag != 0) : true;

  if (bf) {
    const ushort_t* A = (const ushort_t*)Ain;
    for (int t = tid; t < 64 * 16; t += 256) {
      int r = t >> 4, c8 = t & 15;
      float f[8];
      if (r0 + r < n) {
        uint4 v = *reinterpret_cast<const uint4*>(&A[(size_t)(r0 + r) * D + c8 * 8]);
        f[0] = bflo(v.x); f[1] = bfhi(v.x);
        f[2] = bflo(v.y); f[3] = bfhi(v.y);
        f[4] = bflo(v.z); f[5] = bfhi(v.z);
        f[6] = bflo(v.w); f[7] = bfhi(v.w);
      } else {
        #pragma unroll
        for (int j = 0; j < 8; j++) f[j] = 0.f;
      }
      #pragma unroll
      for (int j = 0; j < 8; j++) lin[r * 132 + c8 * 8 + j] = f[j];
    }
  } else {
    const float* A = (const float*)Ain;
    for (int t = tid; t < 64 * 32; t += 256) {
      int r = t >> 5, c4 = t & 31;
      float4 v = make_float4(0.f, 0.f, 0.f, 0.f);
      if (r0 + r < n) v = *reinterpret_cast<const float4*>(&A[(size_t)(r0 + r) * D + c4 * 4]);
      *reinterpret_cast<float4*>(&lin[r * 132 + c4 * 4]) = v;
    }
  }
  __syncthreads();

  const int cg = tid & 15, rg = tid >> 4;
  const int c0 = cg * 8;
  float acc[4][8];
  #pragma unroll
  for (int i = 0; i < 4; i++)
    #pragma unroll
    for (int j = 0; j < 8; j++) acc[i][j] = 0.f;

  for (int k = 0; k < 128; k += 4) {
    float4 a[4];
    #pragma unroll
    for (int i = 0; i < 4; i++)
      a[i] = *reinterpret_cast<const float4*>(&lin[(rg * 4 + i) * 132 + k]);
    #pragma unroll
    for (int dk = 0; dk < 4; dk++) {
      float4 w0 = *reinterpret_cast<const float4*>(&Wf[(size_t)(k + dk) * D + c0]);
      float4 w1 = *reinterpret_cast<const float4*>(&Wf[(size_t)(k + dk) * D + c0 + 4]);
      float w[8] = {w0.x, w0.y, w0.z, w0.w, w1.x, w1.y, w1.z, w1.w};
      #pragma unroll
      for (int i = 0; i < 4; i++) {
        float av = (dk == 0) ? a[i].x : (dk == 1) ? a[i].y : (dk == 2) ? a[i].z : a[i].w;
        #pragma unroll
        for (int j = 0; j < 8; j++) acc[i][j] += av * w[j];
      }
    }
  }

  #pragma unroll
  for (int i = 0; i < 4; i++) {
    int r = r0 + rg * 4 + i;
    if (r < n) {
      uint4 p;
      p.x = (uint_t)f2bf(acc[i][0]) | ((uint_t)f2bf(acc[i][1]) << 16);
      p.y = (uint_t)f2bf(acc[i][2]) | ((uint_t)f2bf(acc[i][3]) << 16);
      p.z = (uint_t)f2bf(acc[i][4]) | ((uint_t)f2bf(acc[i][5]) << 16);
      p.w = (uint_t)f2bf(acc[i][6]) | ((uint_t)f2bf(acc[i][7]) << 16);
      *reinterpret_cast<uint4*>(&out[(size_t)r * D + c0]) = p;
    }
  }
}

// ------- aggregation: out[i] = dinv[i]*(h[i]*dinv[i] + sum h[src]*dinv[src]) + b  (bf16 h) -------
__global__ __launch_bounds__(256) void aggregate(const ushort_t* __restrict__ h,
                                                 const int* __restrict__ row,
                                                 const int* __restrict__ csr,
                                                 const float* __restrict__ dinv,
                                                 const float* __restrict__ bias,
                                                 ushort_t* __restrict__ out, int n, int do_elu) {
  const int gid = (blockIdx.x * 256 + threadIdx.x) >> 5;
  const int lane = threadIdx.x & 31;
  if (gid >= n) return;
  const float di = dinv[gid];
  uint2 hv = *reinterpret_cast<const uint2*>(&h[(size_t)gid * D + lane * 4]);
  float ax = bflo(hv.x) * di, ay = bfhi(hv.x) * di;
  float az = bflo(hv.y) * di, aw = bfhi(hv.y) * di;
  const int s = row[gid], e = row[gid + 1];
  for (int idx = s; idx < e; idx++) {
    int src = csr[idx];
    float ds = dinv[src];
    uint2 m = *reinterpret_cast<const uint2*>(&h[(size_t)src * D + lane * 4]);
    ax += bflo(m.x) * ds; ay += bfhi(m.x) * ds;
    az += bflo(m.y) * ds; aw += bfhi(m.y) * ds;
  }
  float4 bv = *reinterpret_cast<const float4*>(&bias[lane * 4]);
  float ox = ax * di + bv.x;
  float oy = ay * di + bv.y;
  float oz = az * di + bv.z;
  float ow = aw * di + bv.w;
  if (do_elu) {
    ox = ox > 0.f ? ox : expm1f(ox);
    oy = oy > 0.f ? oy : expm1f(oy);
    oz = oz > 0.f ? oz : expm1f(oz);
    ow = ow > 0.f ? ow : expm1f(ow);
  }
  uint2 o;
  o.x = (uint_t)f2bf(ox) | ((uint_t)f2bf(oy) << 16);
  o.y = (uint_t)f2bf(oz) | ((uint_t)f2bf(ow) << 16);
  *reinterpret_cast<uint2*>(&out[(size_t)gid * D + lane * 4]) = o;
}

// ---------------- pooling (batch sorted; run-length flush) ----------------
__global__ __launch_bounds__(128) void pool_kernel(const ushort_t* __restrict__ h,
                                                   const int* __restrict__ batch,
                                                   float* __restrict__ pooled,
                                                   float* __restrict__ cnt, int n) {
  const int f = threadIdx.x;
  const int start = blockIdx.x * 512;
  if (start >= n) return;
  const int end = min(start + 512, n);
  int curg = batch[start];
  float s = 0.f, run = 0.f;
  for (int i = start; i < end; i++) {
    int g = batch[i];
    if (g != curg) {
      unsafeAtomicAdd(&pooled[curg * D + f], s);
      if (f == 0) unsafeAtomicAdd(&cnt[curg], run);
      s = 0.f; run = 0.f; curg = g;
    }
    s += bf2f(h[(size_t)i * D + f]);
    run += 1.f;
  }
  unsafeAtomicAdd(&pooled[curg * D + f], s);
  if (f == 0) unsafeAtomicAdd(&cnt[curg], run);
}

// ---------------- MLP head: one block per graph (f32 weights, f32 output) ----------------
__global__ __launch_bounds__(64) void mlp_kernel(const float* __restrict__ pooled,
                                                 const float* __restrict__ cnt,
                                                 const float* __restrict__ wf,
                                                 float* __restrict__ out) {
  __shared__ float g[128], h1[64], h2[32];
  const int gi = blockIdx.x, t = threadIdx.x;
  float c = fmaxf(cnt[gi], 1.0f);
  g[t] = pooled[gi * D + t] / c;
  g[t + 64] = pooled[gi * D + 64 + t] / c;
  __syncthreads();
  float a = wf[OFB1 + t];
  for (int k = 0; k < 128; k++) a += g[k] * wf[OFW1 + k * 64 + t];
  h1[t] = fmaxf(a, 0.f);
  __syncthreads();
  if (t < 32) {
    float a2 = wf[OFB2 + t];
    for (int k = 0; k < 64; k++) a2 += h1[k] * wf[OFW2 + k * 32 + t];
    h2[t] = fmaxf(a2, 0.f);
  }
  __syncthreads();
  if (t == 0) {
    float a3 = wf[OFB3];
    for (int k = 0; k < 32; k++) a3 += h2[k] * wf[OFW3 + k];
    out[gi] = a3;   // f32 output — the reference returns float32
  }
}

extern "C" void kernel_launch(void* const* d_in, const int* in_sizes, int n_in,
                              void* d_out, int out_size, void* d_ws, size_t ws_size,
                              hipStream_t stream) {
  (void)n_in; (void)out_size; (void)ws_size;
  const int* ei    = (const int*)d_in[13];
  const int* batch = (const int*)d_in[14];
  const int N = in_sizes[14];
  const int E = in_sizes[13] / 2;

  char* ws = (char*)d_ws;
  size_t off = 0;
  auto take = [&](size_t bytes) -> char* {
    char* p = ws + off;
    off += (bytes + 255) & ~(size_t)255;
    return p;
  };
  int*     flag   = (int*)take(4);
  int*     deg    = (int*)take((size_t)N * 4);
  float*   dinv   = (float*)take((size_t)N * 4);
  int*     row    = (int*)take((size_t)(N + 1) * 4);
  int*     cur    = (int*)take((size_t)N * 4);
  int*     csr    = (int*)take((size_t)E * 4);
  float*   wconv  = (float*)take((size_t)WTOT * 4);
  ushort_t* bufA  = (ushort_t*)take((size_t)N * D * 2);
  ushort_t* bufB  = (ushort_t*)take((size_t)N * D * 2);
  float*   pooled = (float*)take((size_t)NG * D * 4);
  float*   cnt    = (float*)take((size_t)NG * 4);

  hipMemsetAsync(deg, 0, (size_t)N * 4, stream);
  hipMemsetAsync(pooled, 0, (size_t)NG * D * 4, stream);
  hipMemsetAsync(cnt, 0, (size_t)NG * 4, stream);

  detect_kernel<<<1, 256, 0, stream>>>((const ushort_t*)d_in[0], flag);
  convert_params<<<(WTOT + 255) / 256, 256, 0, stream>>>(
      d_in[1], d_in[2], d_in[3], d_in[4], d_in[5], d_in[6], d_in[7], d_in[8],
      d_in[9], d_in[10], d_in[11], d_in[12], flag, wconv);

  deg_kernel<<<(E + 255) / 256, 256, 0, stream>>>(ei, deg, E);
  dinv_kernel<<<(N + 255) / 256, 256, 0, stream>>>(deg, dinv, N);
  scan_kernel<<<1, 1024, 0, stream>>>(deg, row, cur, N);
  fill_kernel<<<(E + 255) / 256, 256, 0, stream>>>(ei, cur, csr, E);

  const int gemm_grid = (N + 63) / 64;
  const int agg_grid = (N * 32 + 255) / 256;

  gemm128<<<gemm_grid, 256, 0, stream>>>(d_in[0], wconv + OW1, bufA, N, flag, 1);
  aggregate<<<agg_grid, 256, 0, stream>>>(bufA, row, csr, dinv, wconv + OB1, bufB, N, 1);
  gemm128<<<gemm_grid, 256, 0, stream>>>((const void*)bufB, wconv + OW2, bufA, N, flag, 0);
  aggregate<<<agg_grid, 256, 0, stream>>>(bufA, row, csr, dinv, wconv + OB2, bufB, N, 1);
  gemm128<<<gemm_grid, 256, 0, stream>>>((const void*)bufB, wconv + OW3, bufA, N, flag, 0);
  aggregate<<<agg_grid, 256, 0, stream>>>(bufA, row, csr, dinv, wconv + OB3, bufB, N, 0);

  pool_kernel<<<(N + 511) / 512, 128, 0, stream>>>(bufB, batch, pooled, cnt, N);
  mlp_kernel<<<NG, 64, 0, stream>>>(pooled, cnt, wconv, (float*)d_out);
}

// Round 4
// 499.164 us; speedup vs baseline: 1.2922x; 1.2922x over previous
//
#include <hip/hip_runtime.h>

#define D 128
#define NG 64

typedef unsigned short ushort_t;
typedef unsigned int uint_t;

__device__ __forceinline__ float bflo(uint_t w) { return __uint_as_float(w << 16); }
__device__ __forceinline__ float bfhi(uint_t w) { return __uint_as_float(w & 0xFFFF0000u); }
__device__ __forceinline__ float bf2f(ushort_t u) { return __uint_as_float(((uint_t)u) << 16); }
__device__ __forceinline__ ushort_t f2bf(float f) {
  uint_t x = __float_as_uint(f);
  x = x + 0x7FFFu + ((x >> 16) & 1u);
  return (ushort_t)(x >> 16);
}

// ---- converted-parameter element offsets (f32 scratch) ----
static constexpr int OW1 = 0, OB1 = 16384, OW2 = 16512, OB2 = 32896, OW3 = 33024,
                     OB3 = 49408, OFW1 = 49536, OFB1 = 57728, OFW2 = 57792,
                     OFB2 = 59840, OFW3 = 59872, OFB3 = 59904, WTOT = 59905;

// ---------------- dtype detection (confirmed f32 in round 3, kept as guard) ----------------
__global__ void detect_kernel(const ushort_t* __restrict__ x, int* __restrict__ flag) {
  __shared__ int bad;
  if (threadIdx.x == 0) bad = 0;
  __syncthreads();
  int b = 0;
  for (int i = threadIdx.x; i < 4096; i += 256) {
    ushort_t u = x[i];
    int e = (u >> 7) & 0xFF;
    float v = bf2f(u);
    if (e == 0xFF || fabsf(v) > 1e6f) b++;
  }
  if (b) atomicAdd(&bad, b);
  __syncthreads();
  if (threadIdx.x == 0) *flag = (bad == 0) ? 1 : 0;
}

// ---------------- convert all params to f32 scratch ----------------
__global__ __launch_bounds__(256) void convert_params(
    const void* W1, const void* b1, const void* W2, const void* b2,
    const void* W3, const void* b3, const void* fw1, const void* fb1,
    const void* fw2, const void* fb2, const void* fw3, const void* fb3,
    const int* __restrict__ flag, float* __restrict__ out) {
  int i = blockIdx.x * 256 + threadIdx.x;
  if (i >= WTOT) return;
  const void* src; int local;
  if      (i < OB1)  { src = W1;  local = i; }
  else if (i < OW2)  { src = b1;  local = i - OB1; }
  else if (i < OB2)  { src = W2;  local = i - OW2; }
  else if (i < OW3)  { src = b2;  local = i - OB2; }
  else if (i < OB3)  { src = W3;  local = i - OW3; }
  else if (i < OFW1) { src = b3;  local = i - OB3; }
  else if (i < OFB1) { src = fw1; local = i - OFW1; }
  else if (i < OFW2) { src = fb1; local = i - OFB1; }
  else if (i < OFB2) { src = fw2; local = i - OFW2; }
  else if (i < OFW3) { src = fb2; local = i - OFB2; }
  else if (i < OFB3) { src = fw3; local = i - OFW3; }
  else               { src = fb3; local = i - OFB3; }
  bool bf = (*flag != 0);
  out[i] = bf ? bf2f(((const ushort_t*)src)[local]) : ((const float*)src)[local];
}

// ---------------- CSR build ----------------
__global__ void deg_kernel(const int* __restrict__ ei, int* __restrict__ deg, int E) {
  int e = blockIdx.x * 256 + threadIdx.x;
  if (e < E) atomicAdd(&deg[ei[E + e]], 1);
}

__global__ void dinv_kernel(const int* __restrict__ deg, float* __restrict__ dinv, int n) {
  int i = blockIdx.x * 256 + threadIdx.x;
  if (i < n) dinv[i] = rsqrtf((float)(deg[i] + 1));  // +1 self loop
}

__global__ __launch_bounds__(1024) void scan_kernel(const int* __restrict__ deg,
                                                    int* __restrict__ row,
                                                    int* __restrict__ cur, int n) {
  __shared__ int partial[1024];
  const int tid = threadIdx.x;
  const int chunk = (n + 1023) / 1024;
  const int lo = min(tid * chunk, n);
  const int hi = min(lo + chunk, n);
  int s = 0;
  for (int i = lo; i < hi; i++) s += deg[i];
  partial[tid] = s;
  __syncthreads();
  for (int off = 1; off < 1024; off <<= 1) {
    int v = (tid >= off) ? partial[tid - off] : 0;
    __syncthreads();
    partial[tid] += v;
    __syncthreads();
  }
  int base = (tid == 0) ? 0 : partial[tid - 1];
  for (int i = lo; i < hi; i++) {
    row[i] = base; cur[i] = base;
    base += deg[i];
  }
  if (tid == 1023) row[n] = partial[1023];
}

__global__ void fill_kernel(const int* __restrict__ ei, int* __restrict__ cur,
                            int* __restrict__ csr, int E) {
  int e = blockIdx.x * 256 + threadIdx.x;
  if (e < E) {
    int src = ei[e];
    int dst = ei[E + e];
    int pos = atomicAdd(&cur[dst], 1);
    csr[pos] = src;
  }
}

// ---------------- GEMM: out[n][128](bf16) = in[n][128] @ Wf[128][128](f32) ----------------
__global__ __launch_bounds__(256) void gemm128(const void* __restrict__ Ain,
                                               const float* __restrict__ Wf,
                                               ushort_t* __restrict__ out, int n,
                                               const int* __restrict__ flag,
                                               int src_is_input) {
  __shared__ float lin[64 * 132];
  const int tid = threadIdx.x;
  const int r0 = blockIdx.x * 64;
  const bool bf = src_is_input ? (*flag != 0) : true;

  if (bf) {
    const ushort_t* A = (const ushort_t*)Ain;
    for (int t = tid; t < 64 * 16; t += 256) {
      int r = t >> 4, c8 = t & 15;
      float f[8];
      if (r0 + r < n) {
        uint4 v = *reinterpret_cast<const uint4*>(&A[(size_t)(r0 + r) * D + c8 * 8]);
        f[0] = bflo(v.x); f[1] = bfhi(v.x);
        f[2] = bflo(v.y); f[3] = bfhi(v.y);
        f[4] = bflo(v.z); f[5] = bfhi(v.z);
        f[6] = bflo(v.w); f[7] = bfhi(v.w);
      } else {
        #pragma unroll
        for (int j = 0; j < 8; j++) f[j] = 0.f;
      }
      #pragma unroll
      for (int j = 0; j < 8; j++) lin[r * 132 + c8 * 8 + j] = f[j];
    }
  } else {
    const float* A = (const float*)Ain;
    for (int t = tid; t < 64 * 32; t += 256) {
      int r = t >> 5, c4 = t & 31;
      float4 v = make_float4(0.f, 0.f, 0.f, 0.f);
      if (r0 + r < n) v = *reinterpret_cast<const float4*>(&A[(size_t)(r0 + r) * D + c4 * 4]);
      *reinterpret_cast<float4*>(&lin[r * 132 + c4 * 4]) = v;
    }
  }
  __syncthreads();

  const int cg = tid & 15, rg = tid >> 4;
  const int c0 = cg * 8;
  float acc[4][8];
  #pragma unroll
  for (int i = 0; i < 4; i++)
    #pragma unroll
    for (int j = 0; j < 8; j++) acc[i][j] = 0.f;

  for (int k = 0; k < 128; k += 4) {
    float4 a[4];
    #pragma unroll
    for (int i = 0; i < 4; i++)
      a[i] = *reinterpret_cast<const float4*>(&lin[(rg * 4 + i) * 132 + k]);
    #pragma unroll
    for (int dk = 0; dk < 4; dk++) {
      float4 w0 = *reinterpret_cast<const float4*>(&Wf[(size_t)(k + dk) * D + c0]);
      float4 w1 = *reinterpret_cast<const float4*>(&Wf[(size_t)(k + dk) * D + c0 + 4]);
      float w[8] = {w0.x, w0.y, w0.z, w0.w, w1.x, w1.y, w1.z, w1.w};
      #pragma unroll
      for (int i = 0; i < 4; i++) {
        float av = (dk == 0) ? a[i].x : (dk == 1) ? a[i].y : (dk == 2) ? a[i].z : a[i].w;
        #pragma unroll
        for (int j = 0; j < 8; j++) acc[i][j] += av * w[j];
      }
    }
  }

  #pragma unroll
  for (int i = 0; i < 4; i++) {
    int r = r0 + rg * 4 + i;
    if (r < n) {
      uint4 p;
      p.x = (uint_t)f2bf(acc[i][0]) | ((uint_t)f2bf(acc[i][1]) << 16);
      p.y = (uint_t)f2bf(acc[i][2]) | ((uint_t)f2bf(acc[i][3]) << 16);
      p.z = (uint_t)f2bf(acc[i][4]) | ((uint_t)f2bf(acc[i][5]) << 16);
      p.w = (uint_t)f2bf(acc[i][6]) | ((uint_t)f2bf(acc[i][7]) << 16);
      *reinterpret_cast<uint4*>(&out[(size_t)r * D + c0]) = p;
    }
  }
}

// ------- aggregation: out[i] = dinv[i]*(h[i]*dinv[i] + sum h[src]*dinv[src]) + b  (bf16 h) -------
__global__ __launch_bounds__(256) void aggregate(const ushort_t* __restrict__ h,
                                                 const int* __restrict__ row,
                                                 const int* __restrict__ csr,
                                                 const float* __restrict__ dinv,
                                                 const float* __restrict__ bias,
                                                 ushort_t* __restrict__ out, int n, int do_elu) {
  const int gid = (blockIdx.x * 256 + threadIdx.x) >> 5;
  const int lane = threadIdx.x & 31;
  if (gid >= n) return;
  const float di = dinv[gid];
  uint2 hv = *reinterpret_cast<const uint2*>(&h[(size_t)gid * D + lane * 4]);
  float ax = bflo(hv.x) * di, ay = bfhi(hv.x) * di;
  float az = bflo(hv.y) * di, aw = bfhi(hv.y) * di;
  const int s = row[gid], e = row[gid + 1];
  int idx = s;
  // unroll-by-2: two independent gather chains in flight
  for (; idx + 1 < e; idx += 2) {
    int s0 = csr[idx], s1 = csr[idx + 1];
    float d0 = dinv[s0], d1 = dinv[s1];
    uint2 m0 = *reinterpret_cast<const uint2*>(&h[(size_t)s0 * D + lane * 4]);
    uint2 m1 = *reinterpret_cast<const uint2*>(&h[(size_t)s1 * D + lane * 4]);
    ax += bflo(m0.x) * d0; ay += bfhi(m0.x) * d0;
    az += bflo(m0.y) * d0; aw += bfhi(m0.y) * d0;
    ax += bflo(m1.x) * d1; ay += bfhi(m1.x) * d1;
    az += bflo(m1.y) * d1; aw += bfhi(m1.y) * d1;
  }
  if (idx < e) {
    int s0 = csr[idx];
    float d0 = dinv[s0];
    uint2 m0 = *reinterpret_cast<const uint2*>(&h[(size_t)s0 * D + lane * 4]);
    ax += bflo(m0.x) * d0; ay += bfhi(m0.x) * d0;
    az += bflo(m0.y) * d0; aw += bfhi(m0.y) * d0;
  }
  float4 bv = *reinterpret_cast<const float4*>(&bias[lane * 4]);
  float ox = ax * di + bv.x;
  float oy = ay * di + bv.y;
  float oz = az * di + bv.z;
  float ow = aw * di + bv.w;
  if (do_elu) {
    ox = ox > 0.f ? ox : expm1f(ox);
    oy = oy > 0.f ? oy : expm1f(oy);
    oz = oz > 0.f ? oz : expm1f(oz);
    ow = ow > 0.f ? ow : expm1f(ow);
  }
  uint2 o;
  o.x = (uint_t)f2bf(ox) | ((uint_t)f2bf(oy) << 16);
  o.y = (uint_t)f2bf(oz) | ((uint_t)f2bf(ow) << 16);
  *reinterpret_cast<uint2*>(&out[(size_t)gid * D + lane * 4]) = o;
}

// ---------------- pooling: 64 nodes/block, 256 threads, run-length + atomic flush ----------------
__global__ __launch_bounds__(256) void pool_kernel(const ushort_t* __restrict__ h,
                                                   const int* __restrict__ batch,
                                                   float* __restrict__ pooled, int n) {
  const int c  = threadIdx.x & 63;   // uint column (2 features)
  const int rl = threadIdx.x >> 6;   // row-lane 0..3
  const int base = blockIdx.x * 64;
  if (base >= n) return;
  const int end = min(base + 64, n);
  float sx = 0.f, sy = 0.f;
  int curg = -1;
  for (int i = base + rl; i < end; i += 4) {
    int g = batch[i];
    if (g != curg) {
      if (curg >= 0) {
        unsafeAtomicAdd(&pooled[curg * D + 2 * c], sx);
        unsafeAtomicAdd(&pooled[curg * D + 2 * c + 1], sy);
      }
      curg = g; sx = 0.f; sy = 0.f;
    }
    uint_t v = *reinterpret_cast<const uint_t*>(&h[(size_t)i * D + 2 * c]);
    sx += bflo(v); sy += bfhi(v);
  }
  if (curg >= 0) {
    unsafeAtomicAdd(&pooled[curg * D + 2 * c], sx);
    unsafeAtomicAdd(&pooled[curg * D + 2 * c + 1], sy);
  }
}

// ---------------- per-graph node counts via binary search (batch sorted) ----------------
__global__ void cnt_kernel(const int* __restrict__ batch, float* __restrict__ cnt, int n) {
  int g = threadIdx.x;  // 64 threads
  int lo = 0, hi = n;
  while (lo < hi) { int mid = (lo + hi) >> 1; if (batch[mid] < g) lo = mid + 1; else hi = mid; }
  int a = lo;
  lo = 0; hi = n;
  while (lo < hi) { int mid = (lo + hi) >> 1; if (batch[mid] < g + 1) lo = mid + 1; else hi = mid; }
  cnt[g] = (float)(lo - a);
}

// ---------------- MLP head: one block per graph (f32 weights, f32 output) ----------------
__global__ __launch_bounds__(64) void mlp_kernel(const float* __restrict__ pooled,
                                                 const float* __restrict__ cnt,
                                                 const float* __restrict__ wf,
                                                 float* __restrict__ out) {
  __shared__ float g[128], h1[64], h2[32];
  const int gi = blockIdx.x, t = threadIdx.x;
  float c = fmaxf(cnt[gi], 1.0f);
  g[t] = pooled[gi * D + t] / c;
  g[t + 64] = pooled[gi * D + 64 + t] / c;
  __syncthreads();
  float a = wf[OFB1 + t];
  for (int k = 0; k < 128; k++) a += g[k] * wf[OFW1 + k * 64 + t];
  h1[t] = fmaxf(a, 0.f);
  __syncthreads();
  if (t < 32) {
    float a2 = wf[OFB2 + t];
    for (int k = 0; k < 64; k++) a2 += h1[k] * wf[OFW2 + k * 32 + t];
    h2[t] = fmaxf(a2, 0.f);
  }
  __syncthreads();
  if (t == 0) {
    float a3 = wf[OFB3];
    for (int k = 0; k < 32; k++) a3 += h2[k] * wf[OFW3 + k];
    out[gi] = a3;   // f32 output
  }
}

extern "C" void kernel_launch(void* const* d_in, const int* in_sizes, int n_in,
                              void* d_out, int out_size, void* d_ws, size_t ws_size,
                              hipStream_t stream) {
  (void)n_in; (void)out_size; (void)ws_size;
  const int* ei    = (const int*)d_in[13];
  const int* batch = (const int*)d_in[14];
  const int N = in_sizes[14];
  const int E = in_sizes[13] / 2;

  char* ws = (char*)d_ws;
  size_t off = 0;
  auto take = [&](size_t bytes) -> char* {
    char* p = ws + off;
    off += (bytes + 255) & ~(size_t)255;
    return p;
  };
  int*     flag   = (int*)take(4);
  int*     deg    = (int*)take((size_t)N * 4);
  float*   dinv   = (float*)take((size_t)N * 4);
  int*     row    = (int*)take((size_t)(N + 1) * 4);
  int*     cur    = (int*)take((size_t)N * 4);
  int*     csr    = (int*)take((size_t)E * 4);
  float*   wconv  = (float*)take((size_t)WTOT * 4);
  ushort_t* bufA  = (ushort_t*)take((size_t)N * D * 2);
  ushort_t* bufB  = (ushort_t*)take((size_t)N * D * 2);
  float*   pooled = (float*)take((size_t)NG * D * 4);
  float*   cnt    = (float*)take((size_t)NG * 4);

  hipMemsetAsync(deg, 0, (size_t)N * 4, stream);
  hipMemsetAsync(pooled, 0, (size_t)NG * D * 4, stream);

  detect_kernel<<<1, 256, 0, stream>>>((const ushort_t*)d_in[0], flag);
  convert_params<<<(WTOT + 255) / 256, 256, 0, stream>>>(
      d_in[1], d_in[2], d_in[3], d_in[4], d_in[5], d_in[6], d_in[7], d_in[8],
      d_in[9], d_in[10], d_in[11], d_in[12], flag, wconv);

  deg_kernel<<<(E + 255) / 256, 256, 0, stream>>>(ei, deg, E);
  dinv_kernel<<<(N + 255) / 256, 256, 0, stream>>>(deg, dinv, N);
  scan_kernel<<<1, 1024, 0, stream>>>(deg, row, cur, N);
  fill_kernel<<<(E + 255) / 256, 256, 0, stream>>>(ei, cur, csr, E);

  const int gemm_grid = (N + 63) / 64;
  const int agg_grid = (N * 32 + 255) / 256;

  gemm128<<<gemm_grid, 256, 0, stream>>>(d_in[0], wconv + OW1, bufA, N, flag, 1);
  aggregate<<<agg_grid, 256, 0, stream>>>(bufA, row, csr, dinv, wconv + OB1, bufB, N, 1);
  gemm128<<<gemm_grid, 256, 0, stream>>>((const void*)bufB, wconv + OW2, bufA, N, flag, 0);
  aggregate<<<agg_grid, 256, 0, stream>>>(bufA, row, csr, dinv, wconv + OB2, bufB, N, 1);
  gemm128<<<gemm_grid, 256, 0, stream>>>((const void*)bufB, wconv + OW3, bufA, N, flag, 0);
  aggregate<<<agg_grid, 256, 0, stream>>>(bufA, row, csr, dinv, wconv + OB3, bufB, N, 0);

  pool_kernel<<<(N + 63) / 64, 256, 0, stream>>>(bufB, batch, pooled, N);
  cnt_kernel<<<1, NG, 0, stream>>>(batch, cnt, N);
  mlp_kernel<<<NG, 64, 0, stream>>>(pooled, cnt, wconv, (float*)d_out);
}

// Round 5
// 404.101 us; speedup vs baseline: 1.5961x; 1.2352x over previous
//
#include <hip/hip_runtime.h>

#define D 128
#define NG 64

#define SCAN_CHUNK 16
#define SCAN_BLOCK 256
#define SCAN_TILE (SCAN_CHUNK * SCAN_BLOCK)  // 4096

typedef unsigned short ushort_t;
typedef unsigned int uint_t;

__device__ __forceinline__ float bflo(uint_t w) { return __uint_as_float(w << 16); }
__device__ __forceinline__ float bfhi(uint_t w) { return __uint_as_float(w & 0xFFFF0000u); }
__device__ __forceinline__ float bf2f(ushort_t u) { return __uint_as_float(((uint_t)u) << 16); }
__device__ __forceinline__ ushort_t f2bf(float f) {
  uint_t x = __float_as_uint(f);
  x = x + 0x7FFFu + ((x >> 16) & 1u);
  return (ushort_t)(x >> 16);
}

// ---- converted-parameter element offsets (f32 scratch) ----
static constexpr int OW1 = 0, OB1 = 16384, OW2 = 16512, OB2 = 32896, OW3 = 33024,
                     OB3 = 49408, OFW1 = 49536, OFB1 = 57728, OFW2 = 57792,
                     OFB2 = 59840, OFW3 = 59872, OFB3 = 59904, WTOT = 59905;

// ---------------- dtype detection (confirmed f32 in round 3, kept as guard) ----------------
__global__ void detect_kernel(const ushort_t* __restrict__ x, int* __restrict__ flag) {
  __shared__ int bad;
  if (threadIdx.x == 0) bad = 0;
  __syncthreads();
  int b = 0;
  for (int i = threadIdx.x; i < 4096; i += 256) {
    ushort_t u = x[i];
    int e = (u >> 7) & 0xFF;
    float v = bf2f(u);
    if (e == 0xFF || fabsf(v) > 1e6f) b++;
  }
  if (b) atomicAdd(&bad, b);
  __syncthreads();
  if (threadIdx.x == 0) *flag = (bad == 0) ? 1 : 0;
}

// ---------------- convert all params to f32 scratch ----------------
__global__ __launch_bounds__(256) void convert_params(
    const void* W1, const void* b1, const void* W2, const void* b2,
    const void* W3, const void* b3, const void* fw1, const void* fb1,
    const void* fw2, const void* fb2, const void* fw3, const void* fb3,
    const int* __restrict__ flag, float* __restrict__ out) {
  int i = blockIdx.x * 256 + threadIdx.x;
  if (i >= WTOT) return;
  const void* src; int local;
  if      (i < OB1)  { src = W1;  local = i; }
  else if (i < OW2)  { src = b1;  local = i - OB1; }
  else if (i < OB2)  { src = W2;  local = i - OW2; }
  else if (i < OW3)  { src = b2;  local = i - OB2; }
  else if (i < OB3)  { src = W3;  local = i - OW3; }
  else if (i < OFW1) { src = b3;  local = i - OB3; }
  else if (i < OFB1) { src = fw1; local = i - OFW1; }
  else if (i < OFW2) { src = fb1; local = i - OFB1; }
  else if (i < OFB2) { src = fw2; local = i - OFW2; }
  else if (i < OFW3) { src = fb2; local = i - OFB2; }
  else if (i < OFB3) { src = fw3; local = i - OFW3; }
  else               { src = fb3; local = i - OFB3; }
  bool bf = (*flag != 0);
  out[i] = bf ? bf2f(((const ushort_t*)src)[local]) : ((const float*)src)[local];
}

// ---------------- CSR build ----------------
__global__ void deg_kernel(const int* __restrict__ ei, int* __restrict__ deg, int E) {
  int e = blockIdx.x * 256 + threadIdx.x;
  if (e < E) atomicAdd(&deg[ei[E + e]], 1);
}

__global__ void dinv_kernel(const int* __restrict__ deg, float* __restrict__ dinv, int n) {
  int i = blockIdx.x * 256 + threadIdx.x;
  if (i < n) dinv[i] = rsqrtf((float)(deg[i] + 1));  // +1 self loop
}

// ---------------- 3-phase device-wide exclusive scan of deg -> row, cur ----------------
__global__ __launch_bounds__(SCAN_BLOCK) void scan_phase1(const int* __restrict__ deg,
                                                          int* __restrict__ blockSum, int n) {
  __shared__ int sh[SCAN_BLOCK];
  const int t = threadIdx.x;
  const int base = blockIdx.x * SCAN_TILE + t * SCAN_CHUNK;
  int s = 0;
  #pragma unroll
  for (int i = 0; i < SCAN_CHUNK; i++) {
    int idx = base + i;
    if (idx < n) s += deg[idx];
  }
  sh[t] = s;
  __syncthreads();
  for (int off = SCAN_BLOCK / 2; off > 0; off >>= 1) {
    if (t < off) sh[t] += sh[t + off];
    __syncthreads();
  }
  if (t == 0) blockSum[blockIdx.x] = sh[0];
}

__global__ void scan_phase2(int* __restrict__ blockSum, int* __restrict__ row, int nb, int n) {
  int acc = 0;
  for (int i = 0; i < nb; i++) { int v = blockSum[i]; blockSum[i] = acc; acc += v; }
  row[n] = acc;
}

__global__ __launch_bounds__(SCAN_BLOCK) void scan_phase3(const int* __restrict__ deg,
                                                          const int* __restrict__ blockSum,
                                                          int* __restrict__ row,
                                                          int* __restrict__ cur, int n) {
  __shared__ int sh[SCAN_BLOCK];
  const int t = threadIdx.x;
  const int base = blockIdx.x * SCAN_TILE + t * SCAN_CHUNK;
  int v[SCAN_CHUNK];
  int s = 0;
  #pragma unroll
  for (int i = 0; i < SCAN_CHUNK; i++) {
    int idx = base + i;
    v[i] = (idx < n) ? deg[idx] : 0;
    s += v[i];
  }
  sh[t] = s;
  __syncthreads();
  // Hillis-Steele inclusive scan over thread sums
  for (int off = 1; off < SCAN_BLOCK; off <<= 1) {
    int val = (t >= off) ? sh[t - off] : 0;
    __syncthreads();
    sh[t] += val;
    __syncthreads();
  }
  int excl = ((t == 0) ? 0 : sh[t - 1]) + blockSum[blockIdx.x];
  #pragma unroll
  for (int i = 0; i < SCAN_CHUNK; i++) {
    int idx = base + i;
    if (idx < n) { row[idx] = excl; cur[idx] = excl; excl += v[i]; }
  }
}

__global__ void fill_kernel(const int* __restrict__ ei, int* __restrict__ cur,
                            int* __restrict__ csr, int E) {
  int e = blockIdx.x * 256 + threadIdx.x;
  if (e < E) {
    int src = ei[e];
    int dst = ei[E + e];
    int pos = atomicAdd(&cur[dst], 1);
    csr[pos] = src;
  }
}

// ---------------- GEMM: out[n][128](bf16) = in[n][128] @ Wf[128][128](f32) ----------------
__global__ __launch_bounds__(256) void gemm128(const void* __restrict__ Ain,
                                               const float* __restrict__ Wf,
                                               ushort_t* __restrict__ out, int n,
                                               const int* __restrict__ flag,
                                               int src_is_input) {
  __shared__ float lin[64 * 132];
  const int tid = threadIdx.x;
  const int r0 = blockIdx.x * 64;
  const bool bf = src_is_input ? (*flag != 0) : true;

  if (bf) {
    const ushort_t* A = (const ushort_t*)Ain;
    for (int t = tid; t < 64 * 16; t += 256) {
      int r = t >> 4, c8 = t & 15;
      float f[8];
      if (r0 + r < n) {
        uint4 v = *reinterpret_cast<const uint4*>(&A[(size_t)(r0 + r) * D + c8 * 8]);
        f[0] = bflo(v.x); f[1] = bfhi(v.x);
        f[2] = bflo(v.y); f[3] = bfhi(v.y);
        f[4] = bflo(v.z); f[5] = bfhi(v.z);
        f[6] = bflo(v.w); f[7] = bfhi(v.w);
      } else {
        #pragma unroll
        for (int j = 0; j < 8; j++) f[j] = 0.f;
      }
      #pragma unroll
      for (int j = 0; j < 8; j++) lin[r * 132 + c8 * 8 + j] = f[j];
    }
  } else {
    const float* A = (const float*)Ain;
    for (int t = tid; t < 64 * 32; t += 256) {
      int r = t >> 5, c4 = t & 31;
      float4 v = make_float4(0.f, 0.f, 0.f, 0.f);
      if (r0 + r < n) v = *reinterpret_cast<const float4*>(&A[(size_t)(r0 + r) * D + c4 * 4]);
      *reinterpret_cast<float4*>(&lin[r * 132 + c4 * 4]) = v;
    }
  }
  __syncthreads();

  const int cg = tid & 15, rg = tid >> 4;
  const int c0 = cg * 8;
  float acc[4][8];
  #pragma unroll
  for (int i = 0; i < 4; i++)
    #pragma unroll
    for (int j = 0; j < 8; j++) acc[i][j] = 0.f;

  for (int k = 0; k < 128; k += 4) {
    float4 a[4];
    #pragma unroll
    for (int i = 0; i < 4; i++)
      a[i] = *reinterpret_cast<const float4*>(&lin[(rg * 4 + i) * 132 + k]);
    #pragma unroll
    for (int dk = 0; dk < 4; dk++) {
      float4 w0 = *reinterpret_cast<const float4*>(&Wf[(size_t)(k + dk) * D + c0]);
      float4 w1 = *reinterpret_cast<const float4*>(&Wf[(size_t)(k + dk) * D + c0 + 4]);
      float w[8] = {w0.x, w0.y, w0.z, w0.w, w1.x, w1.y, w1.z, w1.w};
      #pragma unroll
      for (int i = 0; i < 4; i++) {
        float av = (dk == 0) ? a[i].x : (dk == 1) ? a[i].y : (dk == 2) ? a[i].z : a[i].w;
        #pragma unroll
        for (int j = 0; j < 8; j++) acc[i][j] += av * w[j];
      }
    }
  }

  #pragma unroll
  for (int i = 0; i < 4; i++) {
    int r = r0 + rg * 4 + i;
    if (r < n) {
      uint4 p;
      p.x = (uint_t)f2bf(acc[i][0]) | ((uint_t)f2bf(acc[i][1]) << 16);
      p.y = (uint_t)f2bf(acc[i][2]) | ((uint_t)f2bf(acc[i][3]) << 16);
      p.z = (uint_t)f2bf(acc[i][4]) | ((uint_t)f2bf(acc[i][5]) << 16);
      p.w = (uint_t)f2bf(acc[i][6]) | ((uint_t)f2bf(acc[i][7]) << 16);
      *reinterpret_cast<uint4*>(&out[(size_t)r * D + c0]) = p;
    }
  }
}

// ------- aggregation: out[i] = dinv[i]*(h[i]*dinv[i] + sum h[src]*dinv[src]) + b  (bf16 h) -------
__global__ __launch_bounds__(256) void aggregate(const ushort_t* __restrict__ h,
                                                 const int* __restrict__ row,
                                                 const int* __restrict__ csr,
                                                 const float* __restrict__ dinv,
                                                 const float* __restrict__ bias,
                                                 ushort_t* __restrict__ out, int n, int do_elu) {
  const int gid = (blockIdx.x * 256 + threadIdx.x) >> 5;
  const int lane = threadIdx.x & 31;
  if (gid >= n) return;
  const float di = dinv[gid];
  uint2 hv = *reinterpret_cast<const uint2*>(&h[(size_t)gid * D + lane * 4]);
  float ax = bflo(hv.x) * di, ay = bfhi(hv.x) * di;
  float az = bflo(hv.y) * di, aw = bfhi(hv.y) * di;
  const int s = row[gid], e = row[gid + 1];
  int idx = s;
  for (; idx + 1 < e; idx += 2) {
    int s0 = csr[idx], s1 = csr[idx + 1];
    float d0 = dinv[s0], d1 = dinv[s1];
    uint2 m0 = *reinterpret_cast<const uint2*>(&h[(size_t)s0 * D + lane * 4]);
    uint2 m1 = *reinterpret_cast<const uint2*>(&h[(size_t)s1 * D + lane * 4]);
    ax += bflo(m0.x) * d0; ay += bfhi(m0.x) * d0;
    az += bflo(m0.y) * d0; aw += bfhi(m0.y) * d0;
    ax += bflo(m1.x) * d1; ay += bfhi(m1.x) * d1;
    az += bflo(m1.y) * d1; aw += bfhi(m1.y) * d1;
  }
  if (idx < e) {
    int s0 = csr[idx];
    float d0 = dinv[s0];
    uint2 m0 = *reinterpret_cast<const uint2*>(&h[(size_t)s0 * D + lane * 4]);
    ax += bflo(m0.x) * d0; ay += bfhi(m0.x) * d0;
    az += bflo(m0.y) * d0; aw += bfhi(m0.y) * d0;
  }
  float4 bv = *reinterpret_cast<const float4*>(&bias[lane * 4]);
  float ox = ax * di + bv.x;
  float oy = ay * di + bv.y;
  float oz = az * di + bv.z;
  float ow = aw * di + bv.w;
  if (do_elu) {
    ox = ox > 0.f ? ox : expm1f(ox);
    oy = oy > 0.f ? oy : expm1f(oy);
    oz = oz > 0.f ? oz : expm1f(oz);
    ow = ow > 0.f ? ow : expm1f(ow);
  }
  uint2 o;
  o.x = (uint_t)f2bf(ox) | ((uint_t)f2bf(oy) << 16);
  o.y = (uint_t)f2bf(oz) | ((uint_t)f2bf(ow) << 16);
  *reinterpret_cast<uint2*>(&out[(size_t)gid * D + lane * 4]) = o;
}

// ---------------- pooling: 64 nodes/block, 256 threads, run-length + atomic flush ----------------
__global__ __launch_bounds__(256) void pool_kernel(const ushort_t* __restrict__ h,
                                                   const int* __restrict__ batch,
                                                   float* __restrict__ pooled, int n) {
  const int c  = threadIdx.x & 63;   // uint column (2 features)
  const int rl = threadIdx.x >> 6;   // row-lane 0..3
  const int base = blockIdx.x * 64;
  if (base >= n) return;
  const int end = min(base + 64, n);
  float sx = 0.f, sy = 0.f;
  int curg = -1;
  for (int i = base + rl; i < end; i += 4) {
    int g = batch[i];
    if (g != curg) {
      if (curg >= 0) {
        unsafeAtomicAdd(&pooled[curg * D + 2 * c], sx);
        unsafeAtomicAdd(&pooled[curg * D + 2 * c + 1], sy);
      }
      curg = g; sx = 0.f; sy = 0.f;
    }
    uint_t v = *reinterpret_cast<const uint_t*>(&h[(size_t)i * D + 2 * c]);
    sx += bflo(v); sy += bfhi(v);
  }
  if (curg >= 0) {
    unsafeAtomicAdd(&pooled[curg * D + 2 * c], sx);
    unsafeAtomicAdd(&pooled[curg * D + 2 * c + 1], sy);
  }
}

// ---------------- per-graph node counts via binary search (batch sorted) ----------------
__global__ void cnt_kernel(const int* __restrict__ batch, float* __restrict__ cnt, int n) {
  int g = threadIdx.x;  // 64 threads
  int lo = 0, hi = n;
  while (lo < hi) { int mid = (lo + hi) >> 1; if (batch[mid] < g) lo = mid + 1; else hi = mid; }
  int a = lo;
  lo = 0; hi = n;
  while (lo < hi) { int mid = (lo + hi) >> 1; if (batch[mid] < g + 1) lo = mid + 1; else hi = mid; }
  cnt[g] = (float)(lo - a);
}

// ---------------- MLP head: one block per graph (f32 weights, f32 output) ----------------
__global__ __launch_bounds__(64) void mlp_kernel(const float* __restrict__ pooled,
                                                 const float* __restrict__ cnt,
                                                 const float* __restrict__ wf,
                                                 float* __restrict__ out) {
  __shared__ float g[128], h1[64], h2[32];
  const int gi = blockIdx.x, t = threadIdx.x;
  float c = fmaxf(cnt[gi], 1.0f);
  g[t] = pooled[gi * D + t] / c;
  g[t + 64] = pooled[gi * D + 64 + t] / c;
  __syncthreads();
  float a = wf[OFB1 + t];
  for (int k = 0; k < 128; k++) a += g[k] * wf[OFW1 + k * 64 + t];
  h1[t] = fmaxf(a, 0.f);
  __syncthreads();
  if (t < 32) {
    float a2 = wf[OFB2 + t];
    for (int k = 0; k < 64; k++) a2 += h1[k] * wf[OFW2 + k * 32 + t];
    h2[t] = fmaxf(a2, 0.f);
  }
  __syncthreads();
  if (t == 0) {
    float a3 = wf[OFB3];
    for (int k = 0; k < 32; k++) a3 += h2[k] * wf[OFW3 + k];
    out[gi] = a3;   // f32 output
  }
}

extern "C" void kernel_launch(void* const* d_in, const int* in_sizes, int n_in,
                              void* d_out, int out_size, void* d_ws, size_t ws_size,
                              hipStream_t stream) {
  (void)n_in; (void)out_size; (void)ws_size;
  const int* ei    = (const int*)d_in[13];
  const int* batch = (const int*)d_in[14];
  const int N = in_sizes[14];
  const int E = in_sizes[13] / 2;

  char* ws = (char*)d_ws;
  size_t off = 0;
  auto take = [&](size_t bytes) -> char* {
    char* p = ws + off;
    off += (bytes + 255) & ~(size_t)255;
    return p;
  };
  int*     flag   = (int*)take(4);
  int*     deg    = (int*)take((size_t)N * 4);
  float*   dinv   = (float*)take((size_t)N * 4);
  int*     row    = (int*)take((size_t)(N + 1) * 4);
  int*     cur    = (int*)take((size_t)N * 4);
  int*     csr    = (int*)take((size_t)E * 4);
  float*   wconv  = (float*)take((size_t)WTOT * 4);
  int*     bsum   = (int*)take(1024 * 4);
  ushort_t* bufA  = (ushort_t*)take((size_t)N * D * 2);
  ushort_t* bufB  = (ushort_t*)take((size_t)N * D * 2);
  float*   pooled = (float*)take((size_t)NG * D * 4);
  float*   cnt    = (float*)take((size_t)NG * 4);

  hipMemsetAsync(deg, 0, (size_t)N * 4, stream);
  hipMemsetAsync(pooled, 0, (size_t)NG * D * 4, stream);

  detect_kernel<<<1, 256, 0, stream>>>((const ushort_t*)d_in[0], flag);
  convert_params<<<(WTOT + 255) / 256, 256, 0, stream>>>(
      d_in[1], d_in[2], d_in[3], d_in[4], d_in[5], d_in[6], d_in[7], d_in[8],
      d_in[9], d_in[10], d_in[11], d_in[12], flag, wconv);

  deg_kernel<<<(E + 255) / 256, 256, 0, stream>>>(ei, deg, E);
  dinv_kernel<<<(N + 255) / 256, 256, 0, stream>>>(deg, dinv, N);

  const int nbScan = (N + SCAN_TILE - 1) / SCAN_TILE;
  scan_phase1<<<nbScan, SCAN_BLOCK, 0, stream>>>(deg, bsum, N);
  scan_phase2<<<1, 1, 0, stream>>>(bsum, row, nbScan, N);
  scan_phase3<<<nbScan, SCAN_BLOCK, 0, stream>>>(deg, bsum, row, cur, N);

  fill_kernel<<<(E + 255) / 256, 256, 0, stream>>>(ei, cur, csr, E);

  const int gemm_grid = (N + 63) / 64;
  const int agg_grid = (N * 32 + 255) / 256;

  gemm128<<<gemm_grid, 256, 0, stream>>>(d_in[0], wconv + OW1, bufA, N, flag, 1);
  aggregate<<<agg_grid, 256, 0, stream>>>(bufA, row, csr, dinv, wconv + OB1, bufB, N, 1);
  gemm128<<<gemm_grid, 256, 0, stream>>>((const void*)bufB, wconv + OW2, bufA, N, flag, 0);
  aggregate<<<agg_grid, 256, 0, stream>>>(bufA, row, csr, dinv, wconv + OB2, bufB, N, 1);
  gemm128<<<gemm_grid, 256, 0, stream>>>((const void*)bufB, wconv + OW3, bufA, N, flag, 0);
  aggregate<<<agg_grid, 256, 0, stream>>>(bufA, row, csr, dinv, wconv + OB3, bufB, N, 0);

  pool_kernel<<<(N + 63) / 64, 256, 0, stream>>>(bufB, batch, pooled, N);
  cnt_kernel<<<1, NG, 0, stream>>>(batch, cnt, N);
  mlp_kernel<<<NG, 64, 0, stream>>>(pooled, cnt, wconv, (float*)d_out);
}

// Round 6
// 392.962 us; speedup vs baseline: 1.6414x; 1.0283x over previous
//
#include <hip/hip_runtime.h>

#define D 128
#define NG 64

#define SCAN_CHUNK 16
#define SCAN_BLOCK 256
#define SCAN_TILE (SCAN_CHUNK * SCAN_BLOCK)  // 4096

#define FILL_CHUNKS 128   // edge chunks; grid = FILL_CHUNKS * 8 octile blocks

typedef unsigned short ushort_t;
typedef unsigned int uint_t;

__device__ __forceinline__ float bflo(uint_t w) { return __uint_as_float(w << 16); }
__device__ __forceinline__ float bfhi(uint_t w) { return __uint_as_float(w & 0xFFFF0000u); }
__device__ __forceinline__ float bf2f(ushort_t u) { return __uint_as_float(((uint_t)u) << 16); }
__device__ __forceinline__ ushort_t f2bf(float f) {
  uint_t x = __float_as_uint(f);
  x = x + 0x7FFFu + ((x >> 16) & 1u);
  return (ushort_t)(x >> 16);
}

// ---- converted-parameter element offsets (f32 scratch) ----
static constexpr int OW1 = 0, OB1 = 16384, OW2 = 16512, OB2 = 32896, OW3 = 33024,
                     OB3 = 49408, OFW1 = 49536, OFB1 = 57728, OFW2 = 57792,
                     OFB2 = 59840, OFW3 = 59872, OFB3 = 59904, WTOT = 59905;

// ---------------- dtype detection (confirmed f32 in round 3, kept as guard) ----------------
__global__ void detect_kernel(const ushort_t* __restrict__ x, int* __restrict__ flag) {
  __shared__ int bad;
  if (threadIdx.x == 0) bad = 0;
  __syncthreads();
  int b = 0;
  for (int i = threadIdx.x; i < 4096; i += 256) {
    ushort_t u = x[i];
    int e = (u >> 7) & 0xFF;
    float v = bf2f(u);
    if (e == 0xFF || fabsf(v) > 1e6f) b++;
  }
  if (b) atomicAdd(&bad, b);
  __syncthreads();
  if (threadIdx.x == 0) *flag = (bad == 0) ? 1 : 0;
}

// ---------------- convert all params to f32 scratch ----------------
__global__ __launch_bounds__(256) void convert_params(
    const void* W1, const void* b1, const void* W2, const void* b2,
    const void* W3, const void* b3, const void* fw1, const void* fb1,
    const void* fw2, const void* fb2, const void* fw3, const void* fb3,
    const int* __restrict__ flag, float* __restrict__ out) {
  int i = blockIdx.x * 256 + threadIdx.x;
  if (i >= WTOT) return;
  const void* src; int local;
  if      (i < OB1)  { src = W1;  local = i; }
  else if (i < OW2)  { src = b1;  local = i - OB1; }
  else if (i < OB2)  { src = W2;  local = i - OW2; }
  else if (i < OW3)  { src = b2;  local = i - OB2; }
  else if (i < OB3)  { src = W3;  local = i - OW3; }
  else if (i < OFW1) { src = b3;  local = i - OB3; }
  else if (i < OFB1) { src = fw1; local = i - OFW1; }
  else if (i < OFW2) { src = fb1; local = i - OFB1; }
  else if (i < OFB2) { src = fw2; local = i - OFW2; }
  else if (i < OFW3) { src = fb2; local = i - OFB2; }
  else if (i < OFB3) { src = fw3; local = i - OFW3; }
  else               { src = fb3; local = i - OFB3; }
  bool bf = (*flag != 0);
  out[i] = bf ? bf2f(((const ushort_t*)src)[local]) : ((const float*)src)[local];
}

// ---------------- CSR build, XCD-local ----------------
// Block b: octile (b&7) of dst space, edge chunk (b>>3). Under the %8
// block->XCD round-robin, each deg/cur/csr region is written by ONE XCD ->
// no cross-XCD line ping-pong (round-5 fill had 53MB writeback for 3.2MB data).
__global__ __launch_bounds__(256) void deg_kernel(const int* __restrict__ ei,
                                                  int* __restrict__ deg, int E, int octSize) {
  const int oct = blockIdx.x & 7;
  const int chunkSz = (E + FILL_CHUNKS - 1) / FILL_CHUNKS;
  const int c0 = (blockIdx.x >> 3) * chunkSz;
  const int c1 = min(c0 + chunkSz, E);
  const int lo = oct * octSize, hi = lo + octSize;
  for (int i = c0 + threadIdx.x; i < c1; i += 256) {
    int dst = ei[E + i];
    if (dst >= lo && dst < hi) atomicAdd(&deg[dst], 1);
  }
}

__global__ void dinv_kernel(const int* __restrict__ deg, float* __restrict__ dinv, int n) {
  int i = blockIdx.x * 256 + threadIdx.x;
  if (i < n) dinv[i] = rsqrtf((float)(deg[i] + 1));  // +1 self loop
}

// ---------------- 3-phase device-wide exclusive scan of deg -> row, cur ----------------
__global__ __launch_bounds__(SCAN_BLOCK) void scan_phase1(const int* __restrict__ deg,
                                                          int* __restrict__ blockSum, int n) {
  __shared__ int sh[SCAN_BLOCK];
  const int t = threadIdx.x;
  const int base = blockIdx.x * SCAN_TILE + t * SCAN_CHUNK;
  int s = 0;
  #pragma unroll
  for (int i = 0; i < SCAN_CHUNK; i++) {
    int idx = base + i;
    if (idx < n) s += deg[idx];
  }
  sh[t] = s;
  __syncthreads();
  for (int off = SCAN_BLOCK / 2; off > 0; off >>= 1) {
    if (t < off) sh[t] += sh[t + off];
    __syncthreads();
  }
  if (t == 0) blockSum[blockIdx.x] = sh[0];
}

__global__ void scan_phase2(int* __restrict__ blockSum, int* __restrict__ row, int nb, int n) {
  int acc = 0;
  for (int i = 0; i < nb; i++) { int v = blockSum[i]; blockSum[i] = acc; acc += v; }
  row[n] = acc;
}

__global__ __launch_bounds__(SCAN_BLOCK) void scan_phase3(const int* __restrict__ deg,
                                                          const int* __restrict__ blockSum,
                                                          int* __restrict__ row,
                                                          int* __restrict__ cur, int n) {
  __shared__ int sh[SCAN_BLOCK];
  const int t = threadIdx.x;
  const int base = blockIdx.x * SCAN_TILE + t * SCAN_CHUNK;
  int v[SCAN_CHUNK];
  int s = 0;
  #pragma unroll
  for (int i = 0; i < SCAN_CHUNK; i++) {
    int idx = base + i;
    v[i] = (idx < n) ? deg[idx] : 0;
    s += v[i];
  }
  sh[t] = s;
  __syncthreads();
  for (int off = 1; off < SCAN_BLOCK; off <<= 1) {
    int val = (t >= off) ? sh[t - off] : 0;
    __syncthreads();
    sh[t] += val;
    __syncthreads();
  }
  int excl = ((t == 0) ? 0 : sh[t - 1]) + blockSum[blockIdx.x];
  #pragma unroll
  for (int i = 0; i < SCAN_CHUNK; i++) {
    int idx = base + i;
    if (idx < n) { row[idx] = excl; cur[idx] = excl; excl += v[i]; }
  }
}

__global__ __launch_bounds__(256) void fill_kernel(const int* __restrict__ ei,
                                                   int* __restrict__ cur,
                                                   int* __restrict__ csr, int E, int octSize) {
  const int oct = blockIdx.x & 7;
  const int chunkSz = (E + FILL_CHUNKS - 1) / FILL_CHUNKS;
  const int c0 = (blockIdx.x >> 3) * chunkSz;
  const int c1 = min(c0 + chunkSz, E);
  const int lo = oct * octSize, hi = lo + octSize;
  for (int i = c0 + threadIdx.x; i < c1; i += 256) {
    int dst = ei[E + i];
    if (dst >= lo && dst < hi) {
      int src = ei[i];
      int pos = atomicAdd(&cur[dst], 1);
      csr[pos] = src;
    }
  }
}

// ---------------- GEMM: out[n][128](bf16) = in[n][128] @ Wf[128][128](f32) ----------------
__global__ __launch_bounds__(256) void gemm128(const void* __restrict__ Ain,
                                               const float* __restrict__ Wf,
                                               ushort_t* __restrict__ out, int n,
                                               const int* __restrict__ flag,
                                               int src_is_input) {
  __shared__ float lin[64 * 132];
  const int tid = threadIdx.x;
  const int r0 = blockIdx.x * 64;
  const bool bf = src_is_input ? (*flag != 0) : true;

  if (bf) {
    const ushort_t* A = (const ushort_t*)Ain;
    for (int t = tid; t < 64 * 16; t += 256) {
      int r = t >> 4, c8 = t & 15;
      float f[8];
      if (r0 + r < n) {
        uint4 v = *reinterpret_cast<const uint4*>(&A[(size_t)(r0 + r) * D + c8 * 8]);
        f[0] = bflo(v.x); f[1] = bfhi(v.x);
        f[2] = bflo(v.y); f[3] = bfhi(v.y);
        f[4] = bflo(v.z); f[5] = bfhi(v.z);
        f[6] = bflo(v.w); f[7] = bfhi(v.w);
      } else {
        #pragma unroll
        for (int j = 0; j < 8; j++) f[j] = 0.f;
      }
      #pragma unroll
      for (int j = 0; j < 8; j++) lin[r * 132 + c8 * 8 + j] = f[j];
    }
  } else {
    const float* A = (const float*)Ain;
    for (int t = tid; t < 64 * 32; t += 256) {
      int r = t >> 5, c4 = t & 31;
      float4 v = make_float4(0.f, 0.f, 0.f, 0.f);
      if (r0 + r < n) v = *reinterpret_cast<const float4*>(&A[(size_t)(r0 + r) * D + c4 * 4]);
      *reinterpret_cast<float4*>(&lin[r * 132 + c4 * 4]) = v;
    }
  }
  __syncthreads();

  const int cg = tid & 15, rg = tid >> 4;
  const int c0 = cg * 8;
  float acc[4][8];
  #pragma unroll
  for (int i = 0; i < 4; i++)
    #pragma unroll
    for (int j = 0; j < 8; j++) acc[i][j] = 0.f;

  for (int k = 0; k < 128; k += 4) {
    float4 a[4];
    #pragma unroll
    for (int i = 0; i < 4; i++)
      a[i] = *reinterpret_cast<const float4*>(&lin[(rg * 4 + i) * 132 + k]);
    #pragma unroll
    for (int dk = 0; dk < 4; dk++) {
      float4 w0 = *reinterpret_cast<const float4*>(&Wf[(size_t)(k + dk) * D + c0]);
      float4 w1 = *reinterpret_cast<const float4*>(&Wf[(size_t)(k + dk) * D + c0 + 4]);
      float w[8] = {w0.x, w0.y, w0.z, w0.w, w1.x, w1.y, w1.z, w1.w};
      #pragma unroll
      for (int i = 0; i < 4; i++) {
        float av = (dk == 0) ? a[i].x : (dk == 1) ? a[i].y : (dk == 2) ? a[i].z : a[i].w;
        #pragma unroll
        for (int j = 0; j < 8; j++) acc[i][j] += av * w[j];
      }
    }
  }

  #pragma unroll
  for (int i = 0; i < 4; i++) {
    int r = r0 + rg * 4 + i;
    if (r < n) {
      uint4 p;
      p.x = (uint_t)f2bf(acc[i][0]) | ((uint_t)f2bf(acc[i][1]) << 16);
      p.y = (uint_t)f2bf(acc[i][2]) | ((uint_t)f2bf(acc[i][3]) << 16);
      p.z = (uint_t)f2bf(acc[i][4]) | ((uint_t)f2bf(acc[i][5]) << 16);
      p.w = (uint_t)f2bf(acc[i][6]) | ((uint_t)f2bf(acc[i][7]) << 16);
      *reinterpret_cast<uint4*>(&out[(size_t)r * D + c0]) = p;
    }
  }
}

// ------- aggregation: out[i] = dinv[i]*(h[i]*dinv[i] + sum h[src]*dinv[src]) + b  (bf16 h) -------
__global__ __launch_bounds__(256) void aggregate(const ushort_t* __restrict__ h,
                                                 const int* __restrict__ row,
                                                 const int* __restrict__ csr,
                                                 const float* __restrict__ dinv,
                                                 const float* __restrict__ bias,
                                                 ushort_t* __restrict__ out, int n, int do_elu) {
  const int gid = (blockIdx.x * 256 + threadIdx.x) >> 5;
  const int lane = threadIdx.x & 31;
  if (gid >= n) return;
  const float di = dinv[gid];
  uint2 hv = *reinterpret_cast<const uint2*>(&h[(size_t)gid * D + lane * 4]);
  float ax = bflo(hv.x) * di, ay = bfhi(hv.x) * di;
  float az = bflo(hv.y) * di, aw = bfhi(hv.y) * di;
  const int s = row[gid], e = row[gid + 1];
  int idx = s;
  for (; idx + 1 < e; idx += 2) {
    int s0 = csr[idx], s1 = csr[idx + 1];
    float d0 = dinv[s0], d1 = dinv[s1];
    uint2 m0 = *reinterpret_cast<const uint2*>(&h[(size_t)s0 * D + lane * 4]);
    uint2 m1 = *reinterpret_cast<const uint2*>(&h[(size_t)s1 * D + lane * 4]);
    ax += bflo(m0.x) * d0; ay += bfhi(m0.x) * d0;
    az += bflo(m0.y) * d0; aw += bfhi(m0.y) * d0;
    ax += bflo(m1.x) * d1; ay += bfhi(m1.x) * d1;
    az += bflo(m1.y) * d1; aw += bfhi(m1.y) * d1;
  }
  if (idx < e) {
    int s0 = csr[idx];
    float d0 = dinv[s0];
    uint2 m0 = *reinterpret_cast<const uint2*>(&h[(size_t)s0 * D + lane * 4]);
    ax += bflo(m0.x) * d0; ay += bfhi(m0.x) * d0;
    az += bflo(m0.y) * d0; aw += bfhi(m0.y) * d0;
  }
  float4 bv = *reinterpret_cast<const float4*>(&bias[lane * 4]);
  float ox = ax * di + bv.x;
  float oy = ay * di + bv.y;
  float oz = az * di + bv.z;
  float ow = aw * di + bv.w;
  if (do_elu) {
    ox = ox > 0.f ? ox : expm1f(ox);
    oy = oy > 0.f ? oy : expm1f(oy);
    oz = oz > 0.f ? oz : expm1f(oz);
    ow = ow > 0.f ? ow : expm1f(ow);
  }
  uint2 o;
  o.x = (uint_t)f2bf(ox) | ((uint_t)f2bf(oy) << 16);
  o.y = (uint_t)f2bf(oz) | ((uint_t)f2bf(ow) << 16);
  *reinterpret_cast<uint2*>(&out[(size_t)gid * D + lane * 4]) = o;
}

// ---------------- pooling: 64 nodes/block, 256 threads, run-length + atomic flush ----------------
__global__ __launch_bounds__(256) void pool_kernel(const ushort_t* __restrict__ h,
                                                   const int* __restrict__ batch,
                                                   float* __restrict__ pooled, int n) {
  const int c  = threadIdx.x & 63;   // uint column (2 features)
  const int rl = threadIdx.x >> 6;   // row-lane 0..3
  const int base = blockIdx.x * 64;
  if (base >= n) return;
  const int end = min(base + 64, n);
  float sx = 0.f, sy = 0.f;
  int curg = -1;
  for (int i = base + rl; i < end; i += 4) {
    int g = batch[i];
    if (g != curg) {
      if (curg >= 0) {
        unsafeAtomicAdd(&pooled[curg * D + 2 * c], sx);
        unsafeAtomicAdd(&pooled[curg * D + 2 * c + 1], sy);
      }
      curg = g; sx = 0.f; sy = 0.f;
    }
    uint_t v = *reinterpret_cast<const uint_t*>(&h[(size_t)i * D + 2 * c]);
    sx += bflo(v); sy += bfhi(v);
  }
  if (curg >= 0) {
    unsafeAtomicAdd(&pooled[curg * D + 2 * c], sx);
    unsafeAtomicAdd(&pooled[curg * D + 2 * c + 1], sy);
  }
}

// ---------------- per-graph node counts via binary search (batch sorted) ----------------
__global__ void cnt_kernel(const int* __restrict__ batch, float* __restrict__ cnt, int n) {
  int g = threadIdx.x;  // 64 threads
  int lo = 0, hi = n;
  while (lo < hi) { int mid = (lo + hi) >> 1; if (batch[mid] < g) lo = mid + 1; else hi = mid; }
  int a = lo;
  lo = 0; hi = n;
  while (lo < hi) { int mid = (lo + hi) >> 1; if (batch[mid] < g + 1) lo = mid + 1; else hi = mid; }
  cnt[g] = (float)(lo - a);
}

// ---------------- MLP head: one block per graph (f32 weights, f32 output) ----------------
__global__ __launch_bounds__(64) void mlp_kernel(const float* __restrict__ pooled,
                                                 const float* __restrict__ cnt,
                                                 const float* __restrict__ wf,
                                                 float* __restrict__ out) {
  __shared__ float g[128], h1[64], h2[32];
  const int gi = blockIdx.x, t = threadIdx.x;
  float c = fmaxf(cnt[gi], 1.0f);
  g[t] = pooled[gi * D + t] / c;
  g[t + 64] = pooled[gi * D + 64 + t] / c;
  __syncthreads();
  float a = wf[OFB1 + t];
  for (int k = 0; k < 128; k++) a += g[k] * wf[OFW1 + k * 64 + t];
  h1[t] = fmaxf(a, 0.f);
  __syncthreads();
  if (t < 32) {
    float a2 = wf[OFB2 + t];
    for (int k = 0; k < 64; k++) a2 += h1[k] * wf[OFW2 + k * 32 + t];
    h2[t] = fmaxf(a2, 0.f);
  }
  __syncthreads();
  if (t == 0) {
    float a3 = wf[OFB3];
    for (int k = 0; k < 32; k++) a3 += h2[k] * wf[OFW3 + k];
    out[gi] = a3;   // f32 output
  }
}

extern "C" void kernel_launch(void* const* d_in, const int* in_sizes, int n_in,
                              void* d_out, int out_size, void* d_ws, size_t ws_size,
                              hipStream_t stream) {
  (void)n_in; (void)out_size; (void)ws_size;
  const int* ei    = (const int*)d_in[13];
  const int* batch = (const int*)d_in[14];
  const int N = in_sizes[14];
  const int E = in_sizes[13] / 2;
  const int octSize = (N + 7) / 8;

  char* ws = (char*)d_ws;
  size_t off = 0;
  auto take = [&](size_t bytes) -> char* {
    char* p = ws + off;
    off += (bytes + 255) & ~(size_t)255;
    return p;
  };
  int*     flag   = (int*)take(4);
  int*     deg    = (int*)take((size_t)N * 4);
  float*   dinv   = (float*)take((size_t)N * 4);
  int*     row    = (int*)take((size_t)(N + 1) * 4);
  int*     cur    = (int*)take((size_t)N * 4);
  int*     csr    = (int*)take((size_t)E * 4);
  float*   wconv  = (float*)take((size_t)WTOT * 4);
  int*     bsum   = (int*)take(1024 * 4);
  ushort_t* bufA  = (ushort_t*)take((size_t)N * D * 2);
  ushort_t* bufB  = (ushort_t*)take((size_t)N * D * 2);
  float*   pooled = (float*)take((size_t)NG * D * 4);
  float*   cnt    = (float*)take((size_t)NG * 4);

  hipMemsetAsync(deg, 0, (size_t)N * 4, stream);
  hipMemsetAsync(pooled, 0, (size_t)NG * D * 4, stream);

  detect_kernel<<<1, 256, 0, stream>>>((const ushort_t*)d_in[0], flag);
  convert_params<<<(WTOT + 255) / 256, 256, 0, stream>>>(
      d_in[1], d_in[2], d_in[3], d_in[4], d_in[5], d_in[6], d_in[7], d_in[8],
      d_in[9], d_in[10], d_in[11], d_in[12], flag, wconv);

  deg_kernel<<<FILL_CHUNKS * 8, 256, 0, stream>>>(ei, deg, E, octSize);
  dinv_kernel<<<(N + 255) / 256, 256, 0, stream>>>(deg, dinv, N);

  const int nbScan = (N + SCAN_TILE - 1) / SCAN_TILE;
  scan_phase1<<<nbScan, SCAN_BLOCK, 0, stream>>>(deg, bsum, N);
  scan_phase2<<<1, 1, 0, stream>>>(bsum, row, nbScan, N);
  scan_phase3<<<nbScan, SCAN_BLOCK, 0, stream>>>(deg, bsum, row, cur, N);

  fill_kernel<<<FILL_CHUNKS * 8, 256, 0, stream>>>(ei, cur, csr, E, octSize);

  const int gemm_grid = (N + 63) / 64;
  const int agg_grid = (N * 32 + 255) / 256;

  gemm128<<<gemm_grid, 256, 0, stream>>>(d_in[0], wconv + OW1, bufA, N, flag, 1);
  aggregate<<<agg_grid, 256, 0, stream>>>(bufA, row, csr, dinv, wconv + OB1, bufB, N, 1);
  gemm128<<<gemm_grid, 256, 0, stream>>>((const void*)bufB, wconv + OW2, bufA, N, flag, 0);
  aggregate<<<agg_grid, 256, 0, stream>>>(bufA, row, csr, dinv, wconv + OB2, bufB, N, 1);
  gemm128<<<gemm_grid, 256, 0, stream>>>((const void*)bufB, wconv + OW3, bufA, N, flag, 0);
  aggregate<<<agg_grid, 256, 0, stream>>>(bufA, row, csr, dinv, wconv + OB3, bufB, N, 0);

  pool_kernel<<<(N + 63) / 64, 256, 0, stream>>>(bufB, batch, pooled, N);
  cnt_kernel<<<1, NG, 0, stream>>>(batch, cnt, N);
  mlp_kernel<<<NG, 64, 0, stream>>>(pooled, cnt, wconv, (float*)d_out);
}

// Round 7
// 367.647 us; speedup vs baseline: 1.7544x; 1.0689x over previous
//
#include <hip/hip_runtime.h>

#define D 128
#define NG 64

#define SCAN_CHUNK 16
#define SCAN_BLOCK 256
#define SCAN_TILE (SCAN_CHUNK * SCAN_BLOCK)  // 4096

#define FILL_CHUNKS 128   // edge chunks; grid = FILL_CHUNKS * 8 octile blocks

typedef unsigned short ushort_t;
typedef unsigned int uint_t;

__device__ __forceinline__ float bflo(uint_t w) { return __uint_as_float(w << 16); }
__device__ __forceinline__ float bfhi(uint_t w) { return __uint_as_float(w & 0xFFFF0000u); }
__device__ __forceinline__ float bf2f(ushort_t u) { return __uint_as_float(((uint_t)u) << 16); }
__device__ __forceinline__ ushort_t f2bf(float f) {
  uint_t x = __float_as_uint(f);
  x = x + 0x7FFFu + ((x >> 16) & 1u);
  return (ushort_t)(x >> 16);
}

// ---- converted-parameter element offsets (f32 scratch) ----
static constexpr int OW1 = 0, OB1 = 16384, OW2 = 16512, OB2 = 32896, OW3 = 33024,
                     OB3 = 49408, OFW1 = 49536, OFB1 = 57728, OFW2 = 57792,
                     OFB2 = 59840, OFW3 = 59872, OFB3 = 59904, WTOT = 59905;

// ---------------- dtype detection (confirmed f32 in round 3, kept as guard) ----------------
__global__ void detect_kernel(const ushort_t* __restrict__ x, int* __restrict__ flag) {
  __shared__ int bad;
  if (threadIdx.x == 0) bad = 0;
  __syncthreads();
  int b = 0;
  for (int i = threadIdx.x; i < 4096; i += 256) {
    ushort_t u = x[i];
    int e = (u >> 7) & 0xFF;
    float v = bf2f(u);
    if (e == 0xFF || fabsf(v) > 1e6f) b++;
  }
  if (b) atomicAdd(&bad, b);
  __syncthreads();
  if (threadIdx.x == 0) *flag = (bad == 0) ? 1 : 0;
}

// ---------------- convert all params to f32 scratch ----------------
__global__ __launch_bounds__(256) void convert_params(
    const void* W1, const void* b1, const void* W2, const void* b2,
    const void* W3, const void* b3, const void* fw1, const void* fb1,
    const void* fw2, const void* fb2, const void* fw3, const void* fb3,
    const int* __restrict__ flag, float* __restrict__ out) {
  int i = blockIdx.x * 256 + threadIdx.x;
  if (i >= WTOT) return;
  const void* src; int local;
  if      (i < OB1)  { src = W1;  local = i; }
  else if (i < OW2)  { src = b1;  local = i - OB1; }
  else if (i < OB2)  { src = W2;  local = i - OW2; }
  else if (i < OW3)  { src = b2;  local = i - OB2; }
  else if (i < OB3)  { src = W3;  local = i - OW3; }
  else if (i < OFW1) { src = b3;  local = i - OB3; }
  else if (i < OFB1) { src = fw1; local = i - OFW1; }
  else if (i < OFW2) { src = fb1; local = i - OFB1; }
  else if (i < OFB2) { src = fw2; local = i - OFW2; }
  else if (i < OFW3) { src = fb2; local = i - OFB2; }
  else if (i < OFB3) { src = fw3; local = i - OFW3; }
  else               { src = fb3; local = i - OFB3; }
  bool bf = (*flag != 0);
  out[i] = bf ? bf2f(((const ushort_t*)src)[local]) : ((const float*)src)[local];
}

// ---------------- CSR build, XCD-local (round-5 fix: no cross-XCD line ping-pong) ----------------
__global__ __launch_bounds__(256) void deg_kernel(const int* __restrict__ ei,
                                                  int* __restrict__ deg, int E, int octSize) {
  const int oct = blockIdx.x & 7;
  const int chunkSz = (E + FILL_CHUNKS - 1) / FILL_CHUNKS;
  const int c0 = (blockIdx.x >> 3) * chunkSz;
  const int c1 = min(c0 + chunkSz, E);
  const int lo = oct * octSize, hi = lo + octSize;
  for (int i = c0 + threadIdx.x; i < c1; i += 256) {
    int dst = ei[E + i];
    if (dst >= lo && dst < hi) atomicAdd(&deg[dst], 1);
  }
}

__global__ void dinv_kernel(const int* __restrict__ deg, float* __restrict__ dinv, int n) {
  int i = blockIdx.x * 256 + threadIdx.x;
  if (i < n) dinv[i] = rsqrtf((float)(deg[i] + 1));  // +1 self loop
}

// ---------------- 3-phase device-wide exclusive scan of deg -> row, cur ----------------
__global__ __launch_bounds__(SCAN_BLOCK) void scan_phase1(const int* __restrict__ deg,
                                                          int* __restrict__ blockSum, int n) {
  __shared__ int sh[SCAN_BLOCK];
  const int t = threadIdx.x;
  const int base = blockIdx.x * SCAN_TILE + t * SCAN_CHUNK;
  int s = 0;
  #pragma unroll
  for (int i = 0; i < SCAN_CHUNK; i++) {
    int idx = base + i;
    if (idx < n) s += deg[idx];
  }
  sh[t] = s;
  __syncthreads();
  for (int off = SCAN_BLOCK / 2; off > 0; off >>= 1) {
    if (t < off) sh[t] += sh[t + off];
    __syncthreads();
  }
  if (t == 0) blockSum[blockIdx.x] = sh[0];
}

__global__ void scan_phase2(int* __restrict__ blockSum, int* __restrict__ row, int nb, int n) {
  int acc = 0;
  for (int i = 0; i < nb; i++) { int v = blockSum[i]; blockSum[i] = acc; acc += v; }
  row[n] = acc;
}

__global__ __launch_bounds__(SCAN_BLOCK) void scan_phase3(const int* __restrict__ deg,
                                                          const int* __restrict__ blockSum,
                                                          int* __restrict__ row,
                                                          int* __restrict__ cur, int n) {
  __shared__ int sh[SCAN_BLOCK];
  const int t = threadIdx.x;
  const int base = blockIdx.x * SCAN_TILE + t * SCAN_CHUNK;
  int v[SCAN_CHUNK];
  int s = 0;
  #pragma unroll
  for (int i = 0; i < SCAN_CHUNK; i++) {
    int idx = base + i;
    v[i] = (idx < n) ? deg[idx] : 0;
    s += v[i];
  }
  sh[t] = s;
  __syncthreads();
  for (int off = 1; off < SCAN_BLOCK; off <<= 1) {
    int val = (t >= off) ? sh[t - off] : 0;
    __syncthreads();
    sh[t] += val;
    __syncthreads();
  }
  int excl = ((t == 0) ? 0 : sh[t - 1]) + blockSum[blockIdx.x];
  #pragma unroll
  for (int i = 0; i < SCAN_CHUNK; i++) {
    int idx = base + i;
    if (idx < n) { row[idx] = excl; cur[idx] = excl; excl += v[i]; }
  }
}

__global__ __launch_bounds__(256) void fill_kernel(const int* __restrict__ ei,
                                                   int* __restrict__ cur,
                                                   int* __restrict__ csr, int E, int octSize) {
  const int oct = blockIdx.x & 7;
  const int chunkSz = (E + FILL_CHUNKS - 1) / FILL_CHUNKS;
  const int c0 = (blockIdx.x >> 3) * chunkSz;
  const int c1 = min(c0 + chunkSz, E);
  const int lo = oct * octSize, hi = lo + octSize;
  for (int i = c0 + threadIdx.x; i < c1; i += 256) {
    int dst = ei[E + i];
    if (dst >= lo && dst < hi) {
      int src = ei[i];
      int pos = atomicAdd(&cur[dst], 1);
      csr[pos] = src;
    }
  }
}

// ------- GEMM: out[n][128](bf16) = (in[n][128] @ Wf[128][128]) * dinv[r]  (dinv folded) -------
__global__ __launch_bounds__(256) void gemm128(const void* __restrict__ Ain,
                                               const float* __restrict__ Wf,
                                               const float* __restrict__ dinv,
                                               ushort_t* __restrict__ out, int n,
                                               const int* __restrict__ flag,
                                               int src_is_input) {
  __shared__ float lin[64 * 132];
  const int tid = threadIdx.x;
  const int r0 = blockIdx.x * 64;
  const bool bf = src_is_input ? (*flag != 0) : true;

  if (bf) {
    const ushort_t* A = (const ushort_t*)Ain;
    for (int t = tid; t < 64 * 16; t += 256) {
      int r = t >> 4, c8 = t & 15;
      float f[8];
      if (r0 + r < n) {
        uint4 v = *reinterpret_cast<const uint4*>(&A[(size_t)(r0 + r) * D + c8 * 8]);
        f[0] = bflo(v.x); f[1] = bfhi(v.x);
        f[2] = bflo(v.y); f[3] = bfhi(v.y);
        f[4] = bflo(v.z); f[5] = bfhi(v.z);
        f[6] = bflo(v.w); f[7] = bfhi(v.w);
      } else {
        #pragma unroll
        for (int j = 0; j < 8; j++) f[j] = 0.f;
      }
      #pragma unroll
      for (int j = 0; j < 8; j++) lin[r * 132 + c8 * 8 + j] = f[j];
    }
  } else {
    const float* A = (const float*)Ain;
    for (int t = tid; t < 64 * 32; t += 256) {
      int r = t >> 5, c4 = t & 31;
      float4 v = make_float4(0.f, 0.f, 0.f, 0.f);
      if (r0 + r < n) v = *reinterpret_cast<const float4*>(&A[(size_t)(r0 + r) * D + c4 * 4]);
      *reinterpret_cast<float4*>(&lin[r * 132 + c4 * 4]) = v;
    }
  }
  __syncthreads();

  const int cg = tid & 15, rg = tid >> 4;
  const int c0 = cg * 8;
  float acc[4][8];
  #pragma unroll
  for (int i = 0; i < 4; i++)
    #pragma unroll
    for (int j = 0; j < 8; j++) acc[i][j] = 0.f;

  for (int k = 0; k < 128; k += 4) {
    float4 a[4];
    #pragma unroll
    for (int i = 0; i < 4; i++)
      a[i] = *reinterpret_cast<const float4*>(&lin[(rg * 4 + i) * 132 + k]);
    #pragma unroll
    for (int dk = 0; dk < 4; dk++) {
      float4 w0 = *reinterpret_cast<const float4*>(&Wf[(size_t)(k + dk) * D + c0]);
      float4 w1 = *reinterpret_cast<const float4*>(&Wf[(size_t)(k + dk) * D + c0 + 4]);
      float w[8] = {w0.x, w0.y, w0.z, w0.w, w1.x, w1.y, w1.z, w1.w};
      #pragma unroll
      for (int i = 0; i < 4; i++) {
        float av = (dk == 0) ? a[i].x : (dk == 1) ? a[i].y : (dk == 2) ? a[i].z : a[i].w;
        #pragma unroll
        for (int j = 0; j < 8; j++) acc[i][j] += av * w[j];
      }
    }
  }

  #pragma unroll
  for (int i = 0; i < 4; i++) {
    int r = r0 + rg * 4 + i;
    if (r < n) {
      float dv = dinv[r];
      uint4 p;
      p.x = (uint_t)f2bf(acc[i][0] * dv) | ((uint_t)f2bf(acc[i][1] * dv) << 16);
      p.y = (uint_t)f2bf(acc[i][2] * dv) | ((uint_t)f2bf(acc[i][3] * dv) << 16);
      p.z = (uint_t)f2bf(acc[i][4] * dv) | ((uint_t)f2bf(acc[i][5] * dv) << 16);
      p.w = (uint_t)f2bf(acc[i][6] * dv) | ((uint_t)f2bf(acc[i][7] * dv) << 16);
      *reinterpret_cast<uint4*>(&out[(size_t)r * D + c0]) = p;
    }
  }
}

// ------- aggregation: h' already scaled by dinv[src]. out[i] = di*(h'[i] + Σ h'[src]) + b -------
// One full 64-lane wave per node (no intra-wave loop divergence); unroll-4 gather chains.
__global__ __launch_bounds__(256) void aggregate(const ushort_t* __restrict__ h,
                                                 const int* __restrict__ row,
                                                 const int* __restrict__ csr,
                                                 const float* __restrict__ dinv,
                                                 const float* __restrict__ bias,
                                                 ushort_t* __restrict__ out, int n, int do_elu) {
  const int gid = (blockIdx.x * 256 + threadIdx.x) >> 6;
  const int lane = threadIdx.x & 63;
  if (gid >= n) return;
  uint_t hv = *reinterpret_cast<const uint_t*>(&h[(size_t)gid * D + lane * 2]);
  float ax = bflo(hv), ay = bfhi(hv);
  const int s = row[gid], e = row[gid + 1];
  int idx = s;
  for (; idx + 3 < e; idx += 4) {
    int s0 = csr[idx], s1 = csr[idx + 1], s2 = csr[idx + 2], s3 = csr[idx + 3];
    uint_t m0 = *reinterpret_cast<const uint_t*>(&h[(size_t)s0 * D + lane * 2]);
    uint_t m1 = *reinterpret_cast<const uint_t*>(&h[(size_t)s1 * D + lane * 2]);
    uint_t m2 = *reinterpret_cast<const uint_t*>(&h[(size_t)s2 * D + lane * 2]);
    uint_t m3 = *reinterpret_cast<const uint_t*>(&h[(size_t)s3 * D + lane * 2]);
    ax += bflo(m0); ay += bfhi(m0);
    ax += bflo(m1); ay += bfhi(m1);
    ax += bflo(m2); ay += bfhi(m2);
    ax += bflo(m3); ay += bfhi(m3);
  }
  for (; idx < e; idx++) {
    int s0 = csr[idx];
    uint_t m0 = *reinterpret_cast<const uint_t*>(&h[(size_t)s0 * D + lane * 2]);
    ax += bflo(m0); ay += bfhi(m0);
  }
  const float di = dinv[gid];
  float2 bv = *reinterpret_cast<const float2*>(&bias[lane * 2]);
  float ox = ax * di + bv.x;
  float oy = ay * di + bv.y;
  if (do_elu) {
    ox = ox > 0.f ? ox : expm1f(ox);
    oy = oy > 0.f ? oy : expm1f(oy);
  }
  uint_t o = (uint_t)f2bf(ox) | ((uint_t)f2bf(oy) << 16);
  *reinterpret_cast<uint_t*>(&out[(size_t)gid * D + lane * 2]) = o;
}

// ---------------- pooling: 64 nodes/block, 256 threads, run-length + atomic flush ----------------
__global__ __launch_bounds__(256) void pool_kernel(const ushort_t* __restrict__ h,
                                                   const int* __restrict__ batch,
                                                   float* __restrict__ pooled, int n) {
  const int c  = threadIdx.x & 63;   // uint column (2 features)
  const int rl = threadIdx.x >> 6;   // row-lane 0..3
  const int base = blockIdx.x * 64;
  if (base >= n) return;
  const int end = min(base + 64, n);
  float sx = 0.f, sy = 0.f;
  int curg = -1;
  for (int i = base + rl; i < end; i += 4) {
    int g = batch[i];
    if (g != curg) {
      if (curg >= 0) {
        unsafeAtomicAdd(&pooled[curg * D + 2 * c], sx);
        unsafeAtomicAdd(&pooled[curg * D + 2 * c + 1], sy);
      }
      curg = g; sx = 0.f; sy = 0.f;
    }
    uint_t v = *reinterpret_cast<const uint_t*>(&h[(size_t)i * D + 2 * c]);
    sx += bflo(v); sy += bfhi(v);
  }
  if (curg >= 0) {
    unsafeAtomicAdd(&pooled[curg * D + 2 * c], sx);
    unsafeAtomicAdd(&pooled[curg * D + 2 * c + 1], sy);
  }
}

// ---------------- per-graph node counts via binary search (batch sorted) ----------------
__global__ void cnt_kernel(const int* __restrict__ batch, float* __restrict__ cnt, int n) {
  int g = threadIdx.x;  // 64 threads
  int lo = 0, hi = n;
  while (lo < hi) { int mid = (lo + hi) >> 1; if (batch[mid] < g) lo = mid + 1; else hi = mid; }
  int a = lo;
  lo = 0; hi = n;
  while (lo < hi) { int mid = (lo + hi) >> 1; if (batch[mid] < g + 1) lo = mid + 1; else hi = mid; }
  cnt[g] = (float)(lo - a);
}

// ---------------- MLP head: one block per graph (f32 weights, f32 output) ----------------
__global__ __launch_bounds__(64) void mlp_kernel(const float* __restrict__ pooled,
                                                 const float* __restrict__ cnt,
                                                 const float* __restrict__ wf,
                                                 float* __restrict__ out) {
  __shared__ float g[128], h1[64], h2[32];
  const int gi = blockIdx.x, t = threadIdx.x;
  float c = fmaxf(cnt[gi], 1.0f);
  g[t] = pooled[gi * D + t] / c;
  g[t + 64] = pooled[gi * D + 64 + t] / c;
  __syncthreads();
  float a = wf[OFB1 + t];
  for (int k = 0; k < 128; k++) a += g[k] * wf[OFW1 + k * 64 + t];
  h1[t] = fmaxf(a, 0.f);
  __syncthreads();
  if (t < 32) {
    float a2 = wf[OFB2 + t];
    for (int k = 0; k < 64; k++) a2 += h1[k] * wf[OFW2 + k * 32 + t];
    h2[t] = fmaxf(a2, 0.f);
  }
  __syncthreads();
  if (t == 0) {
    float a3 = wf[OFB3];
    for (int k = 0; k < 32; k++) a3 += h2[k] * wf[OFW3 + k];
    out[gi] = a3;   // f32 output
  }
}

extern "C" void kernel_launch(void* const* d_in, const int* in_sizes, int n_in,
                              void* d_out, int out_size, void* d_ws, size_t ws_size,
                              hipStream_t stream) {
  (void)n_in; (void)out_size; (void)ws_size;
  const int* ei    = (const int*)d_in[13];
  const int* batch = (const int*)d_in[14];
  const int N = in_sizes[14];
  const int E = in_sizes[13] / 2;
  const int octSize = (N + 7) / 8;

  char* ws = (char*)d_ws;
  size_t off = 0;
  auto take = [&](size_t bytes) -> char* {
    char* p = ws + off;
    off += (bytes + 255) & ~(size_t)255;
    return p;
  };
  int*     flag   = (int*)take(4);
  int*     deg    = (int*)take((size_t)N * 4);
  float*   dinv   = (float*)take((size_t)N * 4);
  int*     row    = (int*)take((size_t)(N + 1) * 4);
  int*     cur    = (int*)take((size_t)N * 4);
  int*     csr    = (int*)take((size_t)E * 4);
  float*   wconv  = (float*)take((size_t)WTOT * 4);
  int*     bsum   = (int*)take(1024 * 4);
  ushort_t* bufA  = (ushort_t*)take((size_t)N * D * 2);
  ushort_t* bufB  = (ushort_t*)take((size_t)N * D * 2);
  float*   pooled = (float*)take((size_t)NG * D * 4);
  float*   cnt    = (float*)take((size_t)NG * 4);

  hipMemsetAsync(deg, 0, (size_t)N * 4, stream);
  hipMemsetAsync(pooled, 0, (size_t)NG * D * 4, stream);

  detect_kernel<<<1, 256, 0, stream>>>((const ushort_t*)d_in[0], flag);
  convert_params<<<(WTOT + 255) / 256, 256, 0, stream>>>(
      d_in[1], d_in[2], d_in[3], d_in[4], d_in[5], d_in[6], d_in[7], d_in[8],
      d_in[9], d_in[10], d_in[11], d_in[12], flag, wconv);

  deg_kernel<<<FILL_CHUNKS * 8, 256, 0, stream>>>(ei, deg, E, octSize);
  dinv_kernel<<<(N + 255) / 256, 256, 0, stream>>>(deg, dinv, N);

  const int nbScan = (N + SCAN_TILE - 1) / SCAN_TILE;
  scan_phase1<<<nbScan, SCAN_BLOCK, 0, stream>>>(deg, bsum, N);
  scan_phase2<<<1, 1, 0, stream>>>(bsum, row, nbScan, N);
  scan_phase3<<<nbScan, SCAN_BLOCK, 0, stream>>>(deg, bsum, row, cur, N);

  fill_kernel<<<FILL_CHUNKS * 8, 256, 0, stream>>>(ei, cur, csr, E, octSize);

  const int gemm_grid = (N + 63) / 64;
  const int agg_grid = (N * 64 + 255) / 256;

  gemm128<<<gemm_grid, 256, 0, stream>>>(d_in[0], wconv + OW1, dinv, bufA, N, flag, 1);
  aggregate<<<agg_grid, 256, 0, stream>>>(bufA, row, csr, dinv, wconv + OB1, bufB, N, 1);
  gemm128<<<gemm_grid, 256, 0, stream>>>((const void*)bufB, wconv + OW2, dinv, bufA, N, flag, 0);
  aggregate<<<agg_grid, 256, 0, stream>>>(bufA, row, csr, dinv, wconv + OB2, bufB, N, 1);
  gemm128<<<gemm_grid, 256, 0, stream>>>((const void*)bufB, wconv + OW3, dinv, bufA, N, flag, 0);
  aggregate<<<agg_grid, 256, 0, stream>>>(bufA, row, csr, dinv, wconv + OB3, bufB, N, 0);

  pool_kernel<<<(N + 63) / 64, 256, 0, stream>>>(bufB, batch, pooled, N);
  cnt_kernel<<<1, NG, 0, stream>>>(batch, cnt, N);
  mlp_kernel<<<NG, 64, 0, stream>>>(pooled, cnt, wconv, (float*)d_out);
}

// Round 8
// 289.129 us; speedup vs baseline: 2.2308x; 1.2716x over previous
//
#include <hip/hip_runtime.h>

#define D 128
#define NG 64

#define SCAN_CHUNK 16
#define SCAN_BLOCK 256
#define SCAN_TILE (SCAN_CHUNK * SCAN_BLOCK)  // 4096

#define FILL_CHUNKS 128   // edge chunks; grid = FILL_CHUNKS * 8 octile blocks

typedef unsigned short ushort_t;
typedef unsigned int uint_t;
typedef __attribute__((ext_vector_type(8))) short short8;
typedef __attribute__((ext_vector_type(4))) float f32x4;

__device__ __forceinline__ float bflo(uint_t w) { return __uint_as_float(w << 16); }
__device__ __forceinline__ float bfhi(uint_t w) { return __uint_as_float(w & 0xFFFF0000u); }
__device__ __forceinline__ float bf2f(ushort_t u) { return __uint_as_float(((uint_t)u) << 16); }
__device__ __forceinline__ ushort_t f2bf(float f) {
  uint_t x = __float_as_uint(f);
  x = x + 0x7FFFu + ((x >> 16) & 1u);
  return (ushort_t)(x >> 16);
}

// ---- converted-parameter element offsets (f32 scratch) ----
static constexpr int OW1 = 0, OB1 = 16384, OW2 = 16512, OB2 = 32896, OW3 = 33024,
                     OB3 = 49408, OFW1 = 49536, OFB1 = 57728, OFW2 = 57792,
                     OFB2 = 59840, OFW3 = 59872, OFB3 = 59904, WTOT = 59905;

// ---------------- dtype detection (confirmed f32 in round 3, kept as guard) ----------------
__global__ void detect_kernel(const ushort_t* __restrict__ x, int* __restrict__ flag) {
  __shared__ int bad;
  if (threadIdx.x == 0) bad = 0;
  __syncthreads();
  int b = 0;
  for (int i = threadIdx.x; i < 4096; i += 256) {
    ushort_t u = x[i];
    int e = (u >> 7) & 0xFF;
    float v = bf2f(u);
    if (e == 0xFF || fabsf(v) > 1e6f) b++;
  }
  if (b) atomicAdd(&bad, b);
  __syncthreads();
  if (threadIdx.x == 0) *flag = (bad == 0) ? 1 : 0;
}

// ---------------- convert all params to f32 scratch ----------------
__global__ __launch_bounds__(256) void convert_params(
    const void* W1, const void* b1, const void* W2, const void* b2,
    const void* W3, const void* b3, const void* fw1, const void* fb1,
    const void* fw2, const void* fb2, const void* fw3, const void* fb3,
    const int* __restrict__ flag, float* __restrict__ out) {
  int i = blockIdx.x * 256 + threadIdx.x;
  if (i >= WTOT) return;
  const void* src; int local;
  if      (i < OB1)  { src = W1;  local = i; }
  else if (i < OW2)  { src = b1;  local = i - OB1; }
  else if (i < OB2)  { src = W2;  local = i - OW2; }
  else if (i < OW3)  { src = b2;  local = i - OB2; }
  else if (i < OB3)  { src = W3;  local = i - OW3; }
  else if (i < OFW1) { src = b3;  local = i - OB3; }
  else if (i < OFB1) { src = fw1; local = i - OFW1; }
  else if (i < OFW2) { src = fb1; local = i - OFB1; }
  else if (i < OFB2) { src = fw2; local = i - OFW2; }
  else if (i < OFW3) { src = fb2; local = i - OFB2; }
  else if (i < OFB3) { src = fw3; local = i - OFW3; }
  else               { src = fb3; local = i - OFB3; }
  bool bf = (*flag != 0);
  out[i] = bf ? bf2f(((const ushort_t*)src)[local]) : ((const float*)src)[local];
}

// ---------------- transpose GCN weights to bf16 N-major for MFMA B-frags ----------------
__global__ __launch_bounds__(256) void wtrans_kernel(const float* __restrict__ wconv,
                                                     ushort_t* __restrict__ wt) {
  int i = blockIdx.x * 256 + threadIdx.x;
  if (i >= 3 * 16384) return;
  int L = i >> 14, rem = i & 16383;
  int nIdx = rem >> 7, k = rem & 127;
  int base = (L == 0) ? OW1 : (L == 1) ? OW2 : OW3;
  wt[i] = f2bf(wconv[base + k * D + nIdx]);   // wt[L][n][k] = W_L[k][n]
}

// ---------------- CSR build, XCD-local (round-5 fix: no cross-XCD line ping-pong) ----------------
__global__ __launch_bounds__(256) void deg_kernel(const int* __restrict__ ei,
                                                  int* __restrict__ deg, int E, int octSize) {
  const int oct = blockIdx.x & 7;
  const int chunkSz = (E + FILL_CHUNKS - 1) / FILL_CHUNKS;
  const int c0 = (blockIdx.x >> 3) * chunkSz;
  const int c1 = min(c0 + chunkSz, E);
  const int lo = oct * octSize, hi = lo + octSize;
  for (int i = c0 + threadIdx.x; i < c1; i += 256) {
    int dst = ei[E + i];
    if (dst >= lo && dst < hi) atomicAdd(&deg[dst], 1);
  }
}

__global__ void dinv_kernel(const int* __restrict__ deg, float* __restrict__ dinv, int n) {
  int i = blockIdx.x * 256 + threadIdx.x;
  if (i < n) dinv[i] = rsqrtf((float)(deg[i] + 1));  // +1 self loop
}

// ---------------- 3-phase device-wide exclusive scan of deg -> row, cur ----------------
__global__ __launch_bounds__(SCAN_BLOCK) void scan_phase1(const int* __restrict__ deg,
                                                          int* __restrict__ blockSum, int n) {
  __shared__ int sh[SCAN_BLOCK];
  const int t = threadIdx.x;
  const int base = blockIdx.x * SCAN_TILE + t * SCAN_CHUNK;
  int s = 0;
  #pragma unroll
  for (int i = 0; i < SCAN_CHUNK; i++) {
    int idx = base + i;
    if (idx < n) s += deg[idx];
  }
  sh[t] = s;
  __syncthreads();
  for (int off = SCAN_BLOCK / 2; off > 0; off >>= 1) {
    if (t < off) sh[t] += sh[t + off];
    __syncthreads();
  }
  if (t == 0) blockSum[blockIdx.x] = sh[0];
}

__global__ void scan_phase2(int* __restrict__ blockSum, int* __restrict__ row, int nb, int n) {
  int acc = 0;
  for (int i = 0; i < nb; i++) { int v = blockSum[i]; blockSum[i] = acc; acc += v; }
  row[n] = acc;
}

__global__ __launch_bounds__(SCAN_BLOCK) void scan_phase3(const int* __restrict__ deg,
                                                          const int* __restrict__ blockSum,
                                                          int* __restrict__ row,
                                                          int* __restrict__ cur, int n) {
  __shared__ int sh[SCAN_BLOCK];
  const int t = threadIdx.x;
  const int base = blockIdx.x * SCAN_TILE + t * SCAN_CHUNK;
  int v[SCAN_CHUNK];
  int s = 0;
  #pragma unroll
  for (int i = 0; i < SCAN_CHUNK; i++) {
    int idx = base + i;
    v[i] = (idx < n) ? deg[idx] : 0;
    s += v[i];
  }
  sh[t] = s;
  __syncthreads();
  for (int off = 1; off < SCAN_BLOCK; off <<= 1) {
    int val = (t >= off) ? sh[t - off] : 0;
    __syncthreads();
    sh[t] += val;
    __syncthreads();
  }
  int excl = ((t == 0) ? 0 : sh[t - 1]) + blockSum[blockIdx.x];
  #pragma unroll
  for (int i = 0; i < SCAN_CHUNK; i++) {
    int idx = base + i;
    if (idx < n) { row[idx] = excl; cur[idx] = excl; excl += v[i]; }
  }
}

__global__ __launch_bounds__(256) void fill_kernel(const int* __restrict__ ei,
                                                   int* __restrict__ cur,
                                                   int* __restrict__ csr, int E, int octSize) {
  const int oct = blockIdx.x & 7;
  const int chunkSz = (E + FILL_CHUNKS - 1) / FILL_CHUNKS;
  const int c0 = (blockIdx.x >> 3) * chunkSz;
  const int c1 = min(c0 + chunkSz, E);
  const int lo = oct * octSize, hi = lo + octSize;
  for (int i = c0 + threadIdx.x; i < c1; i += 256) {
    int dst = ei[E + i];
    if (dst >= lo && dst < hi) {
      int src = ei[i];
      int pos = atomicAdd(&cur[dst], 1);
      csr[pos] = src;
    }
  }
}

// ------- MFMA GEMM: out[n][128](bf16) = (A[n][128] @ W) * dinv[r]  -------
// W given as bf16 N-major Wt[n][k]; staged in LDS with T2 XOR swizzle
// (row stride 256B -> 16-way bank conflict without it). 4 waves x 16-row
// M-tile x 8 N-tiles, 16x16x32 bf16 MFMA (A: row=l&15,k=(l>>4)*8+j;
// B: col=l&15; C/D: col=l&15,row=(l>>4)*4+reg -- m89/m91-verified layouts).
// Epilogue transposes through LDS (reusing W buffer) to keep uint4 stores.
__global__ __launch_bounds__(256) void gemm128_mfma(const void* __restrict__ Ain,
                                                    const ushort_t* __restrict__ Wt,
                                                    const float* __restrict__ dinv,
                                                    ushort_t* __restrict__ out, int n,
                                                    const int* __restrict__ flag,
                                                    int src_is_input) {
  __shared__ ushort_t wlds[128 * 128];  // 32 KB
  const int tid = threadIdx.x;

  {  // stage W, swizzled: 2048 uint4 chunks; dst_chunk = c ^ ((c>>4)&7)
    const uint4* srcp = (const uint4*)Wt;
    uint4* dstp = (uint4*)wlds;
    #pragma unroll
    for (int i = 0; i < 8; i++) {
      int c = tid + i * 256;
      dstp[c ^ ((c >> 4) & 7)] = srcp[c];
    }
  }
  __syncthreads();

  const int w = tid >> 6, lane = tid & 63;
  const int lrow = lane & 15, lk = lane >> 4;
  const int r0 = blockIdx.x * 64 + w * 16;
  const int node = r0 + lrow;
  const bool bf = src_is_input ? (*flag != 0) : true;

  f32x4 acc[8];
  #pragma unroll
  for (int t = 0; t < 8; t++) acc[t] = (f32x4){0.f, 0.f, 0.f, 0.f};

  #pragma unroll
  for (int ks = 0; ks < 4; ks++) {
    short8 af;
    if (node < n) {
      if (bf) {
        af = *reinterpret_cast<const short8*>(
            (const ushort_t*)Ain + (size_t)node * D + ks * 32 + lk * 8);
      } else {
        const float* Af = (const float*)Ain + (size_t)node * D + ks * 32 + lk * 8;
        float4 a0 = *reinterpret_cast<const float4*>(Af);
        float4 a1 = *reinterpret_cast<const float4*>(Af + 4);
        af = (short8){(short)f2bf(a0.x), (short)f2bf(a0.y), (short)f2bf(a0.z), (short)f2bf(a0.w),
                      (short)f2bf(a1.x), (short)f2bf(a1.y), (short)f2bf(a1.z), (short)f2bf(a1.w)};
      }
    } else {
      af = (short8){0, 0, 0, 0, 0, 0, 0, 0};
    }
    #pragma unroll
    for (int t = 0; t < 8; t++) {
      int chunk = (t * 16 + lrow) * 16 + ks * 4 + lk;   // uint4 index: row*16 + kchunk
      int swz = chunk ^ (lrow & 7);                      // row&7 == lrow&7
      short8 bfrag = *reinterpret_cast<const short8*>((const uint4*)wlds + swz);
      acc[t] = __builtin_amdgcn_mfma_f32_16x16x32_bf16(af, bfrag, acc[t], 0, 0, 0);
    }
  }

  __syncthreads();  // all waves done reading W; reuse LDS for epilogue staging

  float dv[4];
  #pragma unroll
  for (int j = 0; j < 4; j++) {
    int r = r0 + lk * 4 + j;
    dv[j] = (r < n) ? dinv[r] : 0.f;
  }
  ushort_t* st = wlds + w * 16 * D;
  #pragma unroll
  for (int t = 0; t < 8; t++) {
    #pragma unroll
    for (int j = 0; j < 4; j++) {
      int rr = lk * 4 + j;
      int idx = rr * D + t * 16 + lrow;
      st[idx ^ ((rr & 7) << 3)] = f2bf(acc[t][j] * dv[j]);
    }
  }
  __syncthreads();

  const int rrow = lane >> 2;
  const int cbase = (lane & 3) * 8;
  #pragma unroll
  for (int it = 0; it < 4; it++) {
    int col = cbase + it * 32;
    int idx = rrow * D + col;
    uint4 v = *reinterpret_cast<const uint4*>(&st[idx ^ ((rrow & 7) << 3)]);
    if (r0 + rrow < n)
      *reinterpret_cast<uint4*>(&out[(size_t)(r0 + rrow) * D + col]) = v;
  }
}

// ------- aggregation: h' already scaled by dinv[src]. out[i] = di*(h'[i] + Σ h'[src]) + b -------
__global__ __launch_bounds__(256) void aggregate(const ushort_t* __restrict__ h,
                                                 const int* __restrict__ row,
                                                 const int* __restrict__ csr,
                                                 const float* __restrict__ dinv,
                                                 const float* __restrict__ bias,
                                                 ushort_t* __restrict__ out, int n, int do_elu) {
  const int gid = (blockIdx.x * 256 + threadIdx.x) >> 6;
  const int lane = threadIdx.x & 63;
  if (gid >= n) return;
  uint_t hv = *reinterpret_cast<const uint_t*>(&h[(size_t)gid * D + lane * 2]);
  float ax = bflo(hv), ay = bfhi(hv);
  const int s = row[gid], e = row[gid + 1];
  int idx = s;
  for (; idx + 3 < e; idx += 4) {
    int s0 = csr[idx], s1 = csr[idx + 1], s2 = csr[idx + 2], s3 = csr[idx + 3];
    uint_t m0 = *reinterpret_cast<const uint_t*>(&h[(size_t)s0 * D + lane * 2]);
    uint_t m1 = *reinterpret_cast<const uint_t*>(&h[(size_t)s1 * D + lane * 2]);
    uint_t m2 = *reinterpret_cast<const uint_t*>(&h[(size_t)s2 * D + lane * 2]);
    uint_t m3 = *reinterpret_cast<const uint_t*>(&h[(size_t)s3 * D + lane * 2]);
    ax += bflo(m0); ay += bfhi(m0);
    ax += bflo(m1); ay += bfhi(m1);
    ax += bflo(m2); ay += bfhi(m2);
    ax += bflo(m3); ay += bfhi(m3);
  }
  for (; idx < e; idx++) {
    int s0 = csr[idx];
    uint_t m0 = *reinterpret_cast<const uint_t*>(&h[(size_t)s0 * D + lane * 2]);
    ax += bflo(m0); ay += bfhi(m0);
  }
  const float di = dinv[gid];
  float2 bv = *reinterpret_cast<const float2*>(&bias[lane * 2]);
  float ox = ax * di + bv.x;
  float oy = ay * di + bv.y;
  if (do_elu) {
    ox = ox > 0.f ? ox : expm1f(ox);
    oy = oy > 0.f ? oy : expm1f(oy);
  }
  uint_t o = (uint_t)f2bf(ox) | ((uint_t)f2bf(oy) << 16);
  *reinterpret_cast<uint_t*>(&out[(size_t)gid * D + lane * 2]) = o;
}

// ---------------- pooling: 64 nodes/block, 256 threads, run-length + atomic flush ----------------
__global__ __launch_bounds__(256) void pool_kernel(const ushort_t* __restrict__ h,
                                                   const int* __restrict__ batch,
                                                   float* __restrict__ pooled, int n) {
  const int c  = threadIdx.x & 63;
  const int rl = threadIdx.x >> 6;
  const int base = blockIdx.x * 64;
  if (base >= n) return;
  const int end = min(base + 64, n);
  float sx = 0.f, sy = 0.f;
  int curg = -1;
  for (int i = base + rl; i < end; i += 4) {
    int g = batch[i];
    if (g != curg) {
      if (curg >= 0) {
        unsafeAtomicAdd(&pooled[curg * D + 2 * c], sx);
        unsafeAtomicAdd(&pooled[curg * D + 2 * c + 1], sy);
      }
      curg = g; sx = 0.f; sy = 0.f;
    }
    uint_t v = *reinterpret_cast<const uint_t*>(&h[(size_t)i * D + 2 * c]);
    sx += bflo(v); sy += bfhi(v);
  }
  if (curg >= 0) {
    unsafeAtomicAdd(&pooled[curg * D + 2 * c], sx);
    unsafeAtomicAdd(&pooled[curg * D + 2 * c + 1], sy);
  }
}

// ---------------- per-graph node counts via binary search (batch sorted) ----------------
__global__ void cnt_kernel(const int* __restrict__ batch, float* __restrict__ cnt, int n) {
  int g = threadIdx.x;
  int lo = 0, hi = n;
  while (lo < hi) { int mid = (lo + hi) >> 1; if (batch[mid] < g) lo = mid + 1; else hi = mid; }
  int a = lo;
  lo = 0; hi = n;
  while (lo < hi) { int mid = (lo + hi) >> 1; if (batch[mid] < g + 1) lo = mid + 1; else hi = mid; }
  cnt[g] = (float)(lo - a);
}

// ---------------- MLP head: one block per graph (f32 weights, f32 output) ----------------
__global__ __launch_bounds__(64) void mlp_kernel(const float* __restrict__ pooled,
                                                 const float* __restrict__ cnt,
                                                 const float* __restrict__ wf,
                                                 float* __restrict__ out) {
  __shared__ float g[128], h1[64], h2[32];
  const int gi = blockIdx.x, t = threadIdx.x;
  float c = fmaxf(cnt[gi], 1.0f);
  g[t] = pooled[gi * D + t] / c;
  g[t + 64] = pooled[gi * D + 64 + t] / c;
  __syncthreads();
  float a = wf[OFB1 + t];
  for (int k = 0; k < 128; k++) a += g[k] * wf[OFW1 + k * 64 + t];
  h1[t] = fmaxf(a, 0.f);
  __syncthreads();
  if (t < 32) {
    float a2 = wf[OFB2 + t];
    for (int k = 0; k < 64; k++) a2 += h1[k] * wf[OFW2 + k * 32 + t];
    h2[t] = fmaxf(a2, 0.f);
  }
  __syncthreads();
  if (t == 0) {
    float a3 = wf[OFB3];
    for (int k = 0; k < 32; k++) a3 += h2[k] * wf[OFW3 + k];
    out[gi] = a3;
  }
}

extern "C" void kernel_launch(void* const* d_in, const int* in_sizes, int n_in,
                              void* d_out, int out_size, void* d_ws, size_t ws_size,
                              hipStream_t stream) {
  (void)n_in; (void)out_size; (void)ws_size;
  const int* ei    = (const int*)d_in[13];
  const int* batch = (const int*)d_in[14];
  const int N = in_sizes[14];
  const int E = in_sizes[13] / 2;
  const int octSize = (N + 7) / 8;

  char* ws = (char*)d_ws;
  size_t off = 0;
  auto take = [&](size_t bytes) -> char* {
    char* p = ws + off;
    off += (bytes + 255) & ~(size_t)255;
    return p;
  };
  int*     flag   = (int*)take(4);
  int*     deg    = (int*)take((size_t)N * 4);
  float*   dinv   = (float*)take((size_t)N * 4);
  int*     row    = (int*)take((size_t)(N + 1) * 4);
  int*     cur    = (int*)take((size_t)N * 4);
  int*     csr    = (int*)take((size_t)E * 4);
  float*   wconv  = (float*)take((size_t)WTOT * 4);
  ushort_t* wt    = (ushort_t*)take((size_t)3 * 16384 * 2);
  int*     bsum   = (int*)take(1024 * 4);
  ushort_t* bufA  = (ushort_t*)take((size_t)N * D * 2);
  ushort_t* bufB  = (ushort_t*)take((size_t)N * D * 2);
  float*   pooled = (float*)take((size_t)NG * D * 4);
  float*   cnt    = (float*)take((size_t)NG * 4);

  hipMemsetAsync(deg, 0, (size_t)N * 4, stream);
  hipMemsetAsync(pooled, 0, (size_t)NG * D * 4, stream);

  detect_kernel<<<1, 256, 0, stream>>>((const ushort_t*)d_in[0], flag);
  convert_params<<<(WTOT + 255) / 256, 256, 0, stream>>>(
      d_in[1], d_in[2], d_in[3], d_in[4], d_in[5], d_in[6], d_in[7], d_in[8],
      d_in[9], d_in[10], d_in[11], d_in[12], flag, wconv);
  wtrans_kernel<<<192, 256, 0, stream>>>(wconv, wt);

  deg_kernel<<<FILL_CHUNKS * 8, 256, 0, stream>>>(ei, deg, E, octSize);
  dinv_kernel<<<(N + 255) / 256, 256, 0, stream>>>(deg, dinv, N);

  const int nbScan = (N + SCAN_TILE - 1) / SCAN_TILE;
  scan_phase1<<<nbScan, SCAN_BLOCK, 0, stream>>>(deg, bsum, N);
  scan_phase2<<<1, 1, 0, stream>>>(bsum, row, nbScan, N);
  scan_phase3<<<nbScan, SCAN_BLOCK, 0, stream>>>(deg, bsum, row, cur, N);

  fill_kernel<<<FILL_CHUNKS * 8, 256, 0, stream>>>(ei, cur, csr, E, octSize);

  const int gemm_grid = (N + 63) / 64;
  const int agg_grid = (N * 64 + 255) / 256;

  gemm128_mfma<<<gemm_grid, 256, 0, stream>>>(d_in[0], wt, dinv, bufA, N, flag, 1);
  aggregate<<<agg_grid, 256, 0, stream>>>(bufA, row, csr, dinv, wconv + OB1, bufB, N, 1);
  gemm128_mfma<<<gemm_grid, 256, 0, stream>>>((const void*)bufB, wt + 16384, dinv, bufA, N, flag, 0);
  aggregate<<<agg_grid, 256, 0, stream>>>(bufA, row, csr, dinv, wconv + OB2, bufB, N, 1);
  gemm128_mfma<<<gemm_grid, 256, 0, stream>>>((const void*)bufB, wt + 32768, dinv, bufA, N, flag, 0);
  aggregate<<<agg_grid, 256, 0, stream>>>(bufA, row, csr, dinv, wconv + OB3, bufB, N, 0);

  pool_kernel<<<(N + 63) / 64, 256, 0, stream>>>(bufB, batch, pooled, N);
  cnt_kernel<<<1, NG, 0, stream>>>(batch, cnt, N);
  mlp_kernel<<<NG, 64, 0, stream>>>(pooled, cnt, wconv, (float*)d_out);
}

// Round 9
// 276.333 us; speedup vs baseline: 2.3341x; 1.0463x over previous
//
#include <hip/hip_runtime.h>

#define D 128
#define NG 64

#define SCAN_CHUNK 16
#define SCAN_BLOCK 256
#define SCAN_TILE (SCAN_CHUNK * SCAN_BLOCK)  // 4096

#define FILL_CHUNKS 128   // edge chunks; grid = FILL_CHUNKS * 8 octile blocks

typedef unsigned short ushort_t;
typedef unsigned int uint_t;
typedef __attribute__((ext_vector_type(8))) short short8;
typedef __attribute__((ext_vector_type(4))) float f32x4;

__device__ __forceinline__ float bflo(uint_t w) { return __uint_as_float(w << 16); }
__device__ __forceinline__ float bfhi(uint_t w) { return __uint_as_float(w & 0xFFFF0000u); }
__device__ __forceinline__ float bf2f(ushort_t u) { return __uint_as_float(((uint_t)u) << 16); }
__device__ __forceinline__ ushort_t f2bf(float f) {
  uint_t x = __float_as_uint(f);
  x = x + 0x7FFFu + ((x >> 16) & 1u);
  return (ushort_t)(x >> 16);
}

// ---- converted-parameter element offsets (f32 scratch) ----
static constexpr int OW1 = 0, OB1 = 16384, OW2 = 16512, OB2 = 32896, OW3 = 33024,
                     OB3 = 49408, OFW1 = 49536, OFB1 = 57728, OFW2 = 57792,
                     OFB2 = 59840, OFW3 = 59872, OFB3 = 59904, WTOT = 59905;

// ---------------- dtype detection (confirmed f32 in round 3, kept as guard) ----------------
__global__ void detect_kernel(const ushort_t* __restrict__ x, int* __restrict__ flag) {
  __shared__ int bad;
  if (threadIdx.x == 0) bad = 0;
  __syncthreads();
  int b = 0;
  for (int i = threadIdx.x; i < 4096; i += 256) {
    ushort_t u = x[i];
    int e = (u >> 7) & 0xFF;
    float v = bf2f(u);
    if (e == 0xFF || fabsf(v) > 1e6f) b++;
  }
  if (b) atomicAdd(&bad, b);
  __syncthreads();
  if (threadIdx.x == 0) *flag = (bad == 0) ? 1 : 0;
}

// ---------------- convert all params to f32 scratch ----------------
__global__ __launch_bounds__(256) void convert_params(
    const void* W1, const void* b1, const void* W2, const void* b2,
    const void* W3, const void* b3, const void* fw1, const void* fb1,
    const void* fw2, const void* fb2, const void* fw3, const void* fb3,
    const int* __restrict__ flag, float* __restrict__ out) {
  int i = blockIdx.x * 256 + threadIdx.x;
  if (i >= WTOT) return;
  const void* src; int local;
  if      (i < OB1)  { src = W1;  local = i; }
  else if (i < OW2)  { src = b1;  local = i - OB1; }
  else if (i < OB2)  { src = W2;  local = i - OW2; }
  else if (i < OW3)  { src = b2;  local = i - OB2; }
  else if (i < OB3)  { src = W3;  local = i - OW3; }
  else if (i < OFW1) { src = b3;  local = i - OB3; }
  else if (i < OFB1) { src = fw1; local = i - OFW1; }
  else if (i < OFW2) { src = fb1; local = i - OFB1; }
  else if (i < OFB2) { src = fw2; local = i - OFW2; }
  else if (i < OFW3) { src = fb2; local = i - OFB2; }
  else if (i < OFB3) { src = fw3; local = i - OFW3; }
  else               { src = fb3; local = i - OFB3; }
  bool bf = (*flag != 0);
  out[i] = bf ? bf2f(((const ushort_t*)src)[local]) : ((const float*)src)[local];
}

// ---------------- transpose GCN weights to bf16 N-major for MFMA B-frags ----------------
__global__ __launch_bounds__(256) void wtrans_kernel(const float* __restrict__ wconv,
                                                     ushort_t* __restrict__ wt) {
  int i = blockIdx.x * 256 + threadIdx.x;
  if (i >= 3 * 16384) return;
  int L = i >> 14, rem = i & 16383;
  int nIdx = rem >> 7, k = rem & 127;
  int base = (L == 0) ? OW1 : (L == 1) ? OW2 : OW3;
  wt[i] = f2bf(wconv[base + k * D + nIdx]);   // wt[L][n][k] = W_L[k][n]
}

// ---------------- CSR build, XCD-local + nontemporal edge stream ----------------
// Octile filtering (round 5) keeps each deg/cur/csr region on ONE XCD's L2.
// Nontemporal ei loads (round 8): the 25.6MB edge stream was evicting dirty
// scattered csr lines mid-kernel -> 31.5MB writeback for 3.2MB of data.
__global__ __launch_bounds__(256) void deg_kernel(const int* __restrict__ ei,
                                                  int* __restrict__ deg, int E, int octSize) {
  const int oct = blockIdx.x & 7;
  const int chunkSz = (E + FILL_CHUNKS - 1) / FILL_CHUNKS;
  const int c0 = (blockIdx.x >> 3) * chunkSz;
  const int c1 = min(c0 + chunkSz, E);
  const int lo = oct * octSize, hi = lo + octSize;
  for (int i = c0 + threadIdx.x; i < c1; i += 256) {
    int dst = __builtin_nontemporal_load(&ei[E + i]);
    if (dst >= lo && dst < hi) atomicAdd(&deg[dst], 1);
  }
}

__global__ void dinv_kernel(const int* __restrict__ deg, float* __restrict__ dinv, int n) {
  int i = blockIdx.x * 256 + threadIdx.x;
  if (i < n) dinv[i] = rsqrtf((float)(deg[i] + 1));  // +1 self loop
}

// ---------------- 3-phase device-wide exclusive scan of deg -> row, cur ----------------
__global__ __launch_bounds__(SCAN_BLOCK) void scan_phase1(const int* __restrict__ deg,
                                                          int* __restrict__ blockSum, int n) {
  __shared__ int sh[SCAN_BLOCK];
  const int t = threadIdx.x;
  const int base = blockIdx.x * SCAN_TILE + t * SCAN_CHUNK;
  int s = 0;
  #pragma unroll
  for (int i = 0; i < SCAN_CHUNK; i++) {
    int idx = base + i;
    if (idx < n) s += deg[idx];
  }
  sh[t] = s;
  __syncthreads();
  for (int off = SCAN_BLOCK / 2; off > 0; off >>= 1) {
    if (t < off) sh[t] += sh[t + off];
    __syncthreads();
  }
  if (t == 0) blockSum[blockIdx.x] = sh[0];
}

__global__ void scan_phase2(int* __restrict__ blockSum, int* __restrict__ row, int nb, int n) {
  int acc = 0;
  for (int i = 0; i < nb; i++) { int v = blockSum[i]; blockSum[i] = acc; acc += v; }
  row[n] = acc;
}

__global__ __launch_bounds__(SCAN_BLOCK) void scan_phase3(const int* __restrict__ deg,
                                                          const int* __restrict__ blockSum,
                                                          int* __restrict__ row,
                                                          int* __restrict__ cur, int n) {
  __shared__ int sh[SCAN_BLOCK];
  const int t = threadIdx.x;
  const int base = blockIdx.x * SCAN_TILE + t * SCAN_CHUNK;
  int v[SCAN_CHUNK];
  int s = 0;
  #pragma unroll
  for (int i = 0; i < SCAN_CHUNK; i++) {
    int idx = base + i;
    v[i] = (idx < n) ? deg[idx] : 0;
    s += v[i];
  }
  sh[t] = s;
  __syncthreads();
  for (int off = 1; off < SCAN_BLOCK; off <<= 1) {
    int val = (t >= off) ? sh[t - off] : 0;
    __syncthreads();
    sh[t] += val;
    __syncthreads();
  }
  int excl = ((t == 0) ? 0 : sh[t - 1]) + blockSum[blockIdx.x];
  #pragma unroll
  for (int i = 0; i < SCAN_CHUNK; i++) {
    int idx = base + i;
    if (idx < n) { row[idx] = excl; cur[idx] = excl; excl += v[i]; }
  }
}

__global__ __launch_bounds__(256) void fill_kernel(const int* __restrict__ ei,
                                                   int* __restrict__ cur,
                                                   int* __restrict__ csr, int E, int octSize) {
  const int oct = blockIdx.x & 7;
  const int chunkSz = (E + FILL_CHUNKS - 1) / FILL_CHUNKS;
  const int c0 = (blockIdx.x >> 3) * chunkSz;
  const int c1 = min(c0 + chunkSz, E);
  const int lo = oct * octSize, hi = lo + octSize;
  for (int i = c0 + threadIdx.x; i < c1; i += 256) {
    int dst = __builtin_nontemporal_load(&ei[E + i]);
    if (dst >= lo && dst < hi) {
      int src = __builtin_nontemporal_load(&ei[i]);
      int pos = atomicAdd(&cur[dst], 1);
      csr[pos] = src;
    }
  }
}

// ------- MFMA GEMM: out[n][128](bf16) = (A[n][128] @ W) * dinv[r]  -------
__global__ __launch_bounds__(256) void gemm128_mfma(const void* __restrict__ Ain,
                                                    const ushort_t* __restrict__ Wt,
                                                    const float* __restrict__ dinv,
                                                    ushort_t* __restrict__ out, int n,
                                                    const int* __restrict__ flag,
                                                    int src_is_input) {
  __shared__ ushort_t wlds[128 * 128];  // 32 KB
  const int tid = threadIdx.x;

  {  // stage W, swizzled: 2048 uint4 chunks; dst_chunk = c ^ ((c>>4)&7)
    const uint4* srcp = (const uint4*)Wt;
    uint4* dstp = (uint4*)wlds;
    #pragma unroll
    for (int i = 0; i < 8; i++) {
      int c = tid + i * 256;
      dstp[c ^ ((c >> 4) & 7)] = srcp[c];
    }
  }
  __syncthreads();

  const int w = tid >> 6, lane = tid & 63;
  const int lrow = lane & 15, lk = lane >> 4;
  const int r0 = blockIdx.x * 64 + w * 16;
  const int node = r0 + lrow;
  const bool bf = src_is_input ? (*flag != 0) : true;

  f32x4 acc[8];
  #pragma unroll
  for (int t = 0; t < 8; t++) acc[t] = (f32x4){0.f, 0.f, 0.f, 0.f};

  #pragma unroll
  for (int ks = 0; ks < 4; ks++) {
    short8 af;
    if (node < n) {
      if (bf) {
        af = *reinterpret_cast<const short8*>(
            (const ushort_t*)Ain + (size_t)node * D + ks * 32 + lk * 8);
      } else {
        const float* Af = (const float*)Ain + (size_t)node * D + ks * 32 + lk * 8;
        float4 a0 = *reinterpret_cast<const float4*>(Af);
        float4 a1 = *reinterpret_cast<const float4*>(Af + 4);
        af = (short8){(short)f2bf(a0.x), (short)f2bf(a0.y), (short)f2bf(a0.z), (short)f2bf(a0.w),
                      (short)f2bf(a1.x), (short)f2bf(a1.y), (short)f2bf(a1.z), (short)f2bf(a1.w)};
      }
    } else {
      af = (short8){0, 0, 0, 0, 0, 0, 0, 0};
    }
    #pragma unroll
    for (int t = 0; t < 8; t++) {
      int chunk = (t * 16 + lrow) * 16 + ks * 4 + lk;
      int swz = chunk ^ (lrow & 7);
      short8 bfrag = *reinterpret_cast<const short8*>((const uint4*)wlds + swz);
      acc[t] = __builtin_amdgcn_mfma_f32_16x16x32_bf16(af, bfrag, acc[t], 0, 0, 0);
    }
  }

  __syncthreads();  // all waves done reading W; reuse LDS for epilogue staging

  float dv[4];
  #pragma unroll
  for (int j = 0; j < 4; j++) {
    int r = r0 + lk * 4 + j;
    dv[j] = (r < n) ? dinv[r] : 0.f;
  }
  ushort_t* st = wlds + w * 16 * D;
  #pragma unroll
  for (int t = 0; t < 8; t++) {
    #pragma unroll
    for (int j = 0; j < 4; j++) {
      int rr = lk * 4 + j;
      int idx = rr * D + t * 16 + lrow;
      st[idx ^ ((rr & 7) << 3)] = f2bf(acc[t][j] * dv[j]);
    }
  }
  __syncthreads();

  const int rrow = lane >> 2;
  const int cbase = (lane & 3) * 8;
  #pragma unroll
  for (int it = 0; it < 4; it++) {
    int col = cbase + it * 32;
    int idx = rrow * D + col;
    uint4 v = *reinterpret_cast<const uint4*>(&st[idx ^ ((rrow & 7) << 3)]);
    if (r0 + rrow < n)
      *reinterpret_cast<uint4*>(&out[(size_t)(r0 + rrow) * D + col]) = v;
  }
}

// ------- aggregation: h' pre-scaled by dinv[src]. out[i] = di*(h'[i] + Σ h'[src]) + b -------
// One 64-lane wave per node; unroll-8 independent gather chains.
__global__ __launch_bounds__(256) void aggregate(const ushort_t* __restrict__ h,
                                                 const int* __restrict__ row,
                                                 const int* __restrict__ csr,
                                                 const float* __restrict__ dinv,
                                                 const float* __restrict__ bias,
                                                 ushort_t* __restrict__ out, int n, int do_elu) {
  const int gid = (blockIdx.x * 256 + threadIdx.x) >> 6;
  const int lane = threadIdx.x & 63;
  if (gid >= n) return;
  uint_t hv = *reinterpret_cast<const uint_t*>(&h[(size_t)gid * D + lane * 2]);
  float ax = bflo(hv), ay = bfhi(hv);
  const int s = row[gid], e = row[gid + 1];
  int idx = s;
  for (; idx + 7 < e; idx += 8) {
    int s0 = csr[idx],     s1 = csr[idx + 1], s2 = csr[idx + 2], s3 = csr[idx + 3];
    int s4 = csr[idx + 4], s5 = csr[idx + 5], s6 = csr[idx + 6], s7 = csr[idx + 7];
    uint_t m0 = *reinterpret_cast<const uint_t*>(&h[(size_t)s0 * D + lane * 2]);
    uint_t m1 = *reinterpret_cast<const uint_t*>(&h[(size_t)s1 * D + lane * 2]);
    uint_t m2 = *reinterpret_cast<const uint_t*>(&h[(size_t)s2 * D + lane * 2]);
    uint_t m3 = *reinterpret_cast<const uint_t*>(&h[(size_t)s3 * D + lane * 2]);
    uint_t m4 = *reinterpret_cast<const uint_t*>(&h[(size_t)s4 * D + lane * 2]);
    uint_t m5 = *reinterpret_cast<const uint_t*>(&h[(size_t)s5 * D + lane * 2]);
    uint_t m6 = *reinterpret_cast<const uint_t*>(&h[(size_t)s6 * D + lane * 2]);
    uint_t m7 = *reinterpret_cast<const uint_t*>(&h[(size_t)s7 * D + lane * 2]);
    ax += bflo(m0); ay += bfhi(m0);
    ax += bflo(m1); ay += bfhi(m1);
    ax += bflo(m2); ay += bfhi(m2);
    ax += bflo(m3); ay += bfhi(m3);
    ax += bflo(m4); ay += bfhi(m4);
    ax += bflo(m5); ay += bfhi(m5);
    ax += bflo(m6); ay += bfhi(m6);
    ax += bflo(m7); ay += bfhi(m7);
  }
  for (; idx + 3 < e; idx += 4) {
    int s0 = csr[idx], s1 = csr[idx + 1], s2 = csr[idx + 2], s3 = csr[idx + 3];
    uint_t m0 = *reinterpret_cast<const uint_t*>(&h[(size_t)s0 * D + lane * 2]);
    uint_t m1 = *reinterpret_cast<const uint_t*>(&h[(size_t)s1 * D + lane * 2]);
    uint_t m2 = *reinterpret_cast<const uint_t*>(&h[(size_t)s2 * D + lane * 2]);
    uint_t m3 = *reinterpret_cast<const uint_t*>(&h[(size_t)s3 * D + lane * 2]);
    ax += bflo(m0); ay += bfhi(m0);
    ax += bflo(m1); ay += bfhi(m1);
    ax += bflo(m2); ay += bfhi(m2);
    ax += bflo(m3); ay += bfhi(m3);
  }
  for (; idx < e; idx++) {
    int s0 = csr[idx];
    uint_t m0 = *reinterpret_cast<const uint_t*>(&h[(size_t)s0 * D + lane * 2]);
    ax += bflo(m0); ay += bfhi(m0);
  }
  const float di = dinv[gid];
  float2 bv = *reinterpret_cast<const float2*>(&bias[lane * 2]);
  float ox = ax * di + bv.x;
  float oy = ay * di + bv.y;
  if (do_elu) {
    ox = ox > 0.f ? ox : expm1f(ox);
    oy = oy > 0.f ? oy : expm1f(oy);
  }
  uint_t o = (uint_t)f2bf(ox) | ((uint_t)f2bf(oy) << 16);
  *reinterpret_cast<uint_t*>(&out[(size_t)gid * D + lane * 2]) = o;
}

// ---------------- pooling: 64 nodes/block, 256 threads, run-length + atomic flush ----------------
__global__ __launch_bounds__(256) void pool_kernel(const ushort_t* __restrict__ h,
                                                   const int* __restrict__ batch,
                                                   float* __restrict__ pooled, int n) {
  const int c  = threadIdx.x & 63;
  const int rl = threadIdx.x >> 6;
  const int base = blockIdx.x * 64;
  if (base >= n) return;
  const int end = min(base + 64, n);
  float sx = 0.f, sy = 0.f;
  int curg = -1;
  for (int i = base + rl; i < end; i += 4) {
    int g = batch[i];
    if (g != curg) {
      if (curg >= 0) {
        unsafeAtomicAdd(&pooled[curg * D + 2 * c], sx);
        unsafeAtomicAdd(&pooled[curg * D + 2 * c + 1], sy);
      }
      curg = g; sx = 0.f; sy = 0.f;
    }
    uint_t v = *reinterpret_cast<const uint_t*>(&h[(size_t)i * D + 2 * c]);
    sx += bflo(v); sy += bfhi(v);
  }
  if (curg >= 0) {
    unsafeAtomicAdd(&pooled[curg * D + 2 * c], sx);
    unsafeAtomicAdd(&pooled[curg * D + 2 * c + 1], sy);
  }
}

// ---------------- per-graph node counts via binary search (batch sorted) ----------------
__global__ void cnt_kernel(const int* __restrict__ batch, float* __restrict__ cnt, int n) {
  int g = threadIdx.x;
  int lo = 0, hi = n;
  while (lo < hi) { int mid = (lo + hi) >> 1; if (batch[mid] < g) lo = mid + 1; else hi = mid; }
  int a = lo;
  lo = 0; hi = n;
  while (lo < hi) { int mid = (lo + hi) >> 1; if (batch[mid] < g + 1) lo = mid + 1; else hi = mid; }
  cnt[g] = (float)(lo - a);
}

// ---------------- MLP head: one block per graph (f32 weights, f32 output) ----------------
__global__ __launch_bounds__(64) void mlp_kernel(const float* __restrict__ pooled,
                                                 const float* __restrict__ cnt,
                                                 const float* __restrict__ wf,
                                                 float* __restrict__ out) {
  __shared__ float g[128], h1[64], h2[32];
  const int gi = blockIdx.x, t = threadIdx.x;
  float c = fmaxf(cnt[gi], 1.0f);
  g[t] = pooled[gi * D + t] / c;
  g[t + 64] = pooled[gi * D + 64 + t] / c;
  __syncthreads();
  float a = wf[OFB1 + t];
  for (int k = 0; k < 128; k++) a += g[k] * wf[OFW1 + k * 64 + t];
  h1[t] = fmaxf(a, 0.f);
  __syncthreads();
  if (t < 32) {
    float a2 = wf[OFB2 + t];
    for (int k = 0; k < 64; k++) a2 += h1[k] * wf[OFW2 + k * 32 + t];
    h2[t] = fmaxf(a2, 0.f);
  }
  __syncthreads();
  if (t == 0) {
    float a3 = wf[OFB3];
    for (int k = 0; k < 32; k++) a3 += h2[k] * wf[OFW3 + k];
    out[gi] = a3;
  }
}

extern "C" void kernel_launch(void* const* d_in, const int* in_sizes, int n_in,
                              void* d_out, int out_size, void* d_ws, size_t ws_size,
                              hipStream_t stream) {
  (void)n_in; (void)out_size; (void)ws_size;
  const int* ei    = (const int*)d_in[13];
  const int* batch = (const int*)d_in[14];
  const int N = in_sizes[14];
  const int E = in_sizes[13] / 2;
  const int octSize = (N + 7) / 8;

  char* ws = (char*)d_ws;
  size_t off = 0;
  auto take = [&](size_t bytes) -> char* {
    char* p = ws + off;
    off += (bytes + 255) & ~(size_t)255;
    return p;
  };
  int*     flag   = (int*)take(4);
  int*     deg    = (int*)take((size_t)N * 4);
  float*   dinv   = (float*)take((size_t)N * 4);
  int*     row    = (int*)take((size_t)(N + 1) * 4);
  int*     cur    = (int*)take((size_t)N * 4);
  int*     csr    = (int*)take((size_t)E * 4);
  float*   wconv  = (float*)take((size_t)WTOT * 4);
  ushort_t* wt    = (ushort_t*)take((size_t)3 * 16384 * 2);
  int*     bsum   = (int*)take(1024 * 4);
  ushort_t* bufA  = (ushort_t*)take((size_t)N * D * 2);
  ushort_t* bufB  = (ushort_t*)take((size_t)N * D * 2);
  float*   pooled = (float*)take((size_t)NG * D * 4);
  float*   cnt    = (float*)take((size_t)NG * 4);

  hipMemsetAsync(deg, 0, (size_t)N * 4, stream);
  hipMemsetAsync(pooled, 0, (size_t)NG * D * 4, stream);

  detect_kernel<<<1, 256, 0, stream>>>((const ushort_t*)d_in[0], flag);
  convert_params<<<(WTOT + 255) / 256, 256, 0, stream>>>(
      d_in[1], d_in[2], d_in[3], d_in[4], d_in[5], d_in[6], d_in[7], d_in[8],
      d_in[9], d_in[10], d_in[11], d_in[12], flag, wconv);
  wtrans_kernel<<<192, 256, 0, stream>>>(wconv, wt);

  deg_kernel<<<FILL_CHUNKS * 8, 256, 0, stream>>>(ei, deg, E, octSize);
  dinv_kernel<<<(N + 255) / 256, 256, 0, stream>>>(deg, dinv, N);

  const int nbScan = (N + SCAN_TILE - 1) / SCAN_TILE;
  scan_phase1<<<nbScan, SCAN_BLOCK, 0, stream>>>(deg, bsum, N);
  scan_phase2<<<1, 1, 0, stream>>>(bsum, row, nbScan, N);
  scan_phase3<<<nbScan, SCAN_BLOCK, 0, stream>>>(deg, bsum, row, cur, N);

  fill_kernel<<<FILL_CHUNKS * 8, 256, 0, stream>>>(ei, cur, csr, E, octSize);

  const int gemm_grid = (N + 63) / 64;
  const int agg_grid = (N * 64 + 255) / 256;

  gemm128_mfma<<<gemm_grid, 256, 0, stream>>>(d_in[0], wt, dinv, bufA, N, flag, 1);
  aggregate<<<agg_grid, 256, 0, stream>>>(bufA, row, csr, dinv, wconv + OB1, bufB, N, 1);
  gemm128_mfma<<<gemm_grid, 256, 0, stream>>>((const void*)bufB, wt + 16384, dinv, bufA, N, flag, 0);
  aggregate<<<agg_grid, 256, 0, stream>>>(bufA, row, csr, dinv, wconv + OB2, bufB, N, 1);
  gemm128_mfma<<<gemm_grid, 256, 0, stream>>>((const void*)bufB, wt + 32768, dinv, bufA, N, flag, 0);
  aggregate<<<agg_grid, 256, 0, stream>>>(bufA, row, csr, dinv, wconv + OB3, bufB, N, 0);

  pool_kernel<<<(N + 63) / 64, 256, 0, stream>>>(bufB, batch, pooled, N);
  cnt_kernel<<<1, NG, 0, stream>>>(batch, cnt, N);
  mlp_kernel<<<NG, 64, 0, stream>>>(pooled, cnt, wconv, (float*)d_out);
}

// Round 11
// 265.069 us; speedup vs baseline: 2.4333x; 1.0425x over previous
//
#include <hip/hip_runtime.h>

#define D 128
#define NG 64

#define SCAN_CHUNK 16
#define SCAN_BLOCK 256
#define SCAN_TILE (SCAN_CHUNK * SCAN_BLOCK)  // 4096

#define FILL_CHUNKS 125   // E=800K -> chunk 6400, 16B-aligned int4 groups

typedef unsigned short ushort_t;
typedef unsigned int uint_t;
typedef __attribute__((ext_vector_type(8))) short short8;
typedef __attribute__((ext_vector_type(4))) float f32x4;
typedef __attribute__((ext_vector_type(4))) int i32x4;   // clang vector: builtin-compatible

__device__ __forceinline__ float bflo(uint_t w) { return __uint_as_float(w << 16); }
__device__ __forceinline__ float bfhi(uint_t w) { return __uint_as_float(w & 0xFFFF0000u); }
__device__ __forceinline__ float bf2f(ushort_t u) { return __uint_as_float(((uint_t)u) << 16); }
__device__ __forceinline__ ushort_t f2bf(float f) {
  uint_t x = __float_as_uint(f);
  x = x + 0x7FFFu + ((x >> 16) & 1u);
  return (ushort_t)(x >> 16);
}

// ---- converted-parameter element offsets (f32 scratch) ----
static constexpr int OW1 = 0, OB1 = 16384, OW2 = 16512, OB2 = 32896, OW3 = 33024,
                     OB3 = 49408, OFW1 = 49536, OFB1 = 57728, OFW2 = 57792,
                     OFB2 = 59840, OFW3 = 59872, OFB3 = 59904, WTOT = 59905;
static constexpr int WT_ELEMS = 3 * 16384;

// ------- fused params kernel: per-block dtype detect + convert + W-transpose -------
__global__ __launch_bounds__(256) void params_kernel(
    const ushort_t* __restrict__ x,
    const void* W1, const void* b1, const void* W2, const void* b2,
    const void* W3, const void* b3, const void* fw1, const void* fb1,
    const void* fw2, const void* fb2, const void* fw3, const void* fb3,
    int* __restrict__ flag, float* __restrict__ wconv, ushort_t* __restrict__ wt) {
  __shared__ int bad;
  if (threadIdx.x == 0) bad = 0;
  __syncthreads();
  int b = 0;
  for (int i = threadIdx.x; i < 4096; i += 256) {
    ushort_t u = x[i];
    int e = (u >> 7) & 0xFF;
    if (e == 0xFF || fabsf(bf2f(u)) > 1e6f) b++;
  }
  if (b) atomicAdd(&bad, b);
  __syncthreads();
  const bool bf = (bad == 0);
  if (blockIdx.x == 0 && threadIdx.x == 0) *flag = bf ? 1 : 0;

  int i = blockIdx.x * 256 + threadIdx.x;
  if (i < WTOT) {
    const void* src; int local;
    if      (i < OB1)  { src = W1;  local = i; }
    else if (i < OW2)  { src = b1;  local = i - OB1; }
    else if (i < OB2)  { src = W2;  local = i - OW2; }
    else if (i < OW3)  { src = b2;  local = i - OB2; }
    else if (i < OB3)  { src = W3;  local = i - OW3; }
    else if (i < OFW1) { src = b3;  local = i - OB3; }
    else if (i < OFB1) { src = fw1; local = i - OFW1; }
    else if (i < OFW2) { src = fb1; local = i - OFB1; }
    else if (i < OFB2) { src = fw2; local = i - OFW2; }
    else if (i < OFW3) { src = fb2; local = i - OFB2; }
    else if (i < OFB3) { src = fw3; local = i - OFW3; }
    else               { src = fb3; local = i - OFB3; }
    wconv[i] = bf ? bf2f(((const ushort_t*)src)[local]) : ((const float*)src)[local];
  } else if (i < WTOT + WT_ELEMS) {
    int j = i - WTOT;
    int L = j >> 14, rem = j & 16383;
    int nIdx = rem >> 7, k = rem & 127;
    const void* src = (L == 0) ? W1 : (L == 1) ? W2 : W3;
    int idx = k * D + nIdx;
    float v = bf ? bf2f(((const ushort_t*)src)[idx]) : ((const float*)src)[idx];
    wt[j] = f2bf(v);   // wt[L][n][k] = W_L[k][n]
  }
}

// ---------------- CSR build, XCD-local octiles + nontemporal int4 edge stream ----------------
__global__ __launch_bounds__(256) void deg_kernel(const int* __restrict__ ei,
                                                  int* __restrict__ deg, int E, int octSize) {
  const int oct = blockIdx.x & 7;
  int chunkSz = ((E + FILL_CHUNKS - 1) / FILL_CHUNKS + 3) & ~3;
  const int c0 = (blockIdx.x >> 3) * chunkSz;
  const int c1 = min(c0 + chunkSz, E);
  const int lo = oct * octSize, hi = lo + octSize;
  if ((E & 3) == 0) {
    const int ng = (c1 - c0) >> 2;
    for (int g = threadIdx.x; g < ng; g += 256) {
      i32x4 d = __builtin_nontemporal_load(
          reinterpret_cast<const i32x4*>(&ei[E + c0 + g * 4]));
      if (d.x >= lo && d.x < hi) atomicAdd(&deg[d.x], 1);
      if (d.y >= lo && d.y < hi) atomicAdd(&deg[d.y], 1);
      if (d.z >= lo && d.z < hi) atomicAdd(&deg[d.z], 1);
      if (d.w >= lo && d.w < hi) atomicAdd(&deg[d.w], 1);
    }
  } else {
    for (int i = c0 + threadIdx.x; i < c1; i += 256) {
      int dst = __builtin_nontemporal_load(&ei[E + i]);
      if (dst >= lo && dst < hi) atomicAdd(&deg[dst], 1);
    }
  }
}

// ---------------- scan phase1: block sums + dinv fused ----------------
__global__ __launch_bounds__(SCAN_BLOCK) void scan_phase1(const int* __restrict__ deg,
                                                          float* __restrict__ dinv,
                                                          int* __restrict__ blockSum, int n) {
  __shared__ int sh[SCAN_BLOCK];
  const int t = threadIdx.x;
  const int base = blockIdx.x * SCAN_TILE + t * SCAN_CHUNK;
  int s = 0;
  #pragma unroll
  for (int i = 0; i < SCAN_CHUNK; i++) {
    int idx = base + i;
    if (idx < n) {
      int dg = deg[idx];
      s += dg;
      dinv[idx] = rsqrtf((float)(dg + 1));  // +1 self loop
    }
  }
  sh[t] = s;
  __syncthreads();
  for (int off = SCAN_BLOCK / 2; off > 0; off >>= 1) {
    if (t < off) sh[t] += sh[t + off];
    __syncthreads();
  }
  if (t == 0) blockSum[blockIdx.x] = sh[0];
}

// ---------------- scan phase3: per-block scan, prefix of blockSums computed inline ----------------
__global__ __launch_bounds__(SCAN_BLOCK) void scan_phase3(const int* __restrict__ deg,
                                                          const int* __restrict__ blockSum,
                                                          int* __restrict__ row,
                                                          int* __restrict__ cur, int n, int nb) {
  __shared__ int sh[SCAN_BLOCK];
  const int t = threadIdx.x;
  const int base = blockIdx.x * SCAN_TILE + t * SCAN_CHUNK;
  int pre = 0;
  for (int bm = 0; bm < (int)blockIdx.x; bm++) pre += blockSum[bm];  // nb<=13, trivial
  int v[SCAN_CHUNK];
  int s = 0;
  #pragma unroll
  for (int i = 0; i < SCAN_CHUNK; i++) {
    int idx = base + i;
    v[i] = (idx < n) ? deg[idx] : 0;
    s += v[i];
  }
  sh[t] = s;
  __syncthreads();
  for (int off = 1; off < SCAN_BLOCK; off <<= 1) {
    int val = (t >= off) ? sh[t - off] : 0;
    __syncthreads();
    sh[t] += val;
    __syncthreads();
  }
  int excl = ((t == 0) ? 0 : sh[t - 1]) + pre;
  #pragma unroll
  for (int i = 0; i < SCAN_CHUNK; i++) {
    int idx = base + i;
    if (idx < n) { row[idx] = excl; cur[idx] = excl; excl += v[i]; }
  }
  if ((int)blockIdx.x == nb - 1 && t == SCAN_BLOCK - 1) row[n] = pre + sh[SCAN_BLOCK - 1];
}

__global__ __launch_bounds__(256) void fill_kernel(const int* __restrict__ ei,
                                                   int* __restrict__ cur,
                                                   int* __restrict__ csr, int E, int octSize) {
  const int oct = blockIdx.x & 7;
  int chunkSz = ((E + FILL_CHUNKS - 1) / FILL_CHUNKS + 3) & ~3;
  const int c0 = (blockIdx.x >> 3) * chunkSz;
  const int c1 = min(c0 + chunkSz, E);
  const int lo = oct * octSize, hi = lo + octSize;
  if ((E & 3) == 0) {
    const int ng = (c1 - c0) >> 2;
    for (int g = threadIdx.x; g < ng; g += 256) {
      const int base = c0 + g * 4;
      i32x4 d = __builtin_nontemporal_load(reinterpret_cast<const i32x4*>(&ei[E + base]));
      bool h0 = d.x >= lo && d.x < hi, h1 = d.y >= lo && d.y < hi;
      bool h2 = d.z >= lo && d.z < hi, h3 = d.w >= lo && d.w < hi;
      if (h0 | h1 | h2 | h3) {
        i32x4 sv = __builtin_nontemporal_load(reinterpret_cast<const i32x4*>(&ei[base]));
        if (h0) csr[atomicAdd(&cur[d.x], 1)] = sv.x;
        if (h1) csr[atomicAdd(&cur[d.y], 1)] = sv.y;
        if (h2) csr[atomicAdd(&cur[d.z], 1)] = sv.z;
        if (h3) csr[atomicAdd(&cur[d.w], 1)] = sv.w;
      }
    }
  } else {
    for (int i = c0 + threadIdx.x; i < c1; i += 256) {
      int dst = __builtin_nontemporal_load(&ei[E + i]);
      if (dst >= lo && dst < hi) {
        int src = __builtin_nontemporal_load(&ei[i]);
        csr[atomicAdd(&cur[dst], 1)] = src;
      }
    }
  }
}

// ------- MFMA GEMM: out[n][128](bf16) = (A[n][128] @ W) * dinv[r]  -------
__global__ __launch_bounds__(256) void gemm128_mfma(const void* __restrict__ Ain,
                                                    const ushort_t* __restrict__ Wt,
                                                    const float* __restrict__ dinv,
                                                    ushort_t* __restrict__ out, int n,
                                                    const int* __restrict__ flag,
                                                    int src_is_input) {
  __shared__ ushort_t wlds[128 * 128];  // 32 KB
  const int tid = threadIdx.x;

  {  // stage W, swizzled: 2048 uint4 chunks; dst_chunk = c ^ ((c>>4)&7)
    const uint4* srcp = (const uint4*)Wt;
    uint4* dstp = (uint4*)wlds;
    #pragma unroll
    for (int i = 0; i < 8; i++) {
      int c = tid + i * 256;
      dstp[c ^ ((c >> 4) & 7)] = srcp[c];
    }
  }
  __syncthreads();

  const int w = tid >> 6, lane = tid & 63;
  const int lrow = lane & 15, lk = lane >> 4;
  const int r0 = blockIdx.x * 64 + w * 16;
  const int node = r0 + lrow;
  const bool bf = src_is_input ? (*flag != 0) : true;

  f32x4 acc[8];
  #pragma unroll
  for (int t = 0; t < 8; t++) acc[t] = (f32x4){0.f, 0.f, 0.f, 0.f};

  #pragma unroll
  for (int ks = 0; ks < 4; ks++) {
    short8 af;
    if (node < n) {
      if (bf) {
        af = *reinterpret_cast<const short8*>(
            (const ushort_t*)Ain + (size_t)node * D + ks * 32 + lk * 8);
      } else {
        const float* Af = (const float*)Ain + (size_t)node * D + ks * 32 + lk * 8;
        float4 a0 = *reinterpret_cast<const float4*>(Af);
        float4 a1 = *reinterpret_cast<const float4*>(Af + 4);
        af = (short8){(short)f2bf(a0.x), (short)f2bf(a0.y), (short)f2bf(a0.z), (short)f2bf(a0.w),
                      (short)f2bf(a1.x), (short)f2bf(a1.y), (short)f2bf(a1.z), (short)f2bf(a1.w)};
      }
    } else {
      af = (short8){0, 0, 0, 0, 0, 0, 0, 0};
    }
    #pragma unroll
    for (int t = 0; t < 8; t++) {
      int chunk = (t * 16 + lrow) * 16 + ks * 4 + lk;
      int swz = chunk ^ (lrow & 7);
      short8 bfrag = *reinterpret_cast<const short8*>((const uint4*)wlds + swz);
      acc[t] = __builtin_amdgcn_mfma_f32_16x16x32_bf16(af, bfrag, acc[t], 0, 0, 0);
    }
  }

  __syncthreads();  // all waves done reading W; reuse LDS for epilogue staging

  float dv[4];
  #pragma unroll
  for (int j = 0; j < 4; j++) {
    int r = r0 + lk * 4 + j;
    dv[j] = (r < n) ? dinv[r] : 0.f;
  }
  ushort_t* st = wlds + w * 16 * D;
  #pragma unroll
  for (int t = 0; t < 8; t++) {
    #pragma unroll
    for (int j = 0; j < 4; j++) {
      int rr = lk * 4 + j;
      int idx = rr * D + t * 16 + lrow;
      st[idx ^ ((rr & 7) << 3)] = f2bf(acc[t][j] * dv[j]);
    }
  }
  __syncthreads();

  const int rrow = lane >> 2;
  const int cbase = (lane & 3) * 8;
  #pragma unroll
  for (int it = 0; it < 4; it++) {
    int col = cbase + it * 32;
    int idx = rrow * D + col;
    uint4 v = *reinterpret_cast<const uint4*>(&st[idx ^ ((rrow & 7) << 3)]);
    if (r0 + rrow < n)
      *reinterpret_cast<uint4*>(&out[(size_t)(r0 + rrow) * D + col]) = v;
  }
}

// ------- aggregation: h' pre-scaled by dinv[src]. out[i] = di*(h'[i] + Σ h'[src]) + b -------
__global__ __launch_bounds__(256) void aggregate(const ushort_t* __restrict__ h,
                                                 const int* __restrict__ row,
                                                 const int* __restrict__ csr,
                                                 const float* __restrict__ dinv,
                                                 const float* __restrict__ bias,
                                                 ushort_t* __restrict__ out, int n, int do_elu) {
  const int wid = (blockIdx.x * 256 + threadIdx.x) >> 6;
  const int nw = (gridDim.x * 256) >> 6;
  const int lane = threadIdx.x & 63;
  float2 bv = *reinterpret_cast<const float2*>(&bias[lane * 2]);
  for (int gid = wid; gid < n; gid += nw) {
    uint_t hv = *reinterpret_cast<const uint_t*>(&h[(size_t)gid * D + lane * 2]);
    float ax = bflo(hv), ay = bfhi(hv);
    const int s = row[gid], e = row[gid + 1];
    int idx = s;
    for (; idx + 7 < e; idx += 8) {
      int s0 = csr[idx],     s1 = csr[idx + 1], s2 = csr[idx + 2], s3 = csr[idx + 3];
      int s4 = csr[idx + 4], s5 = csr[idx + 5], s6 = csr[idx + 6], s7 = csr[idx + 7];
      uint_t m0 = *reinterpret_cast<const uint_t*>(&h[(size_t)s0 * D + lane * 2]);
      uint_t m1 = *reinterpret_cast<const uint_t*>(&h[(size_t)s1 * D + lane * 2]);
      uint_t m2 = *reinterpret_cast<const uint_t*>(&h[(size_t)s2 * D + lane * 2]);
      uint_t m3 = *reinterpret_cast<const uint_t*>(&h[(size_t)s3 * D + lane * 2]);
      uint_t m4 = *reinterpret_cast<const uint_t*>(&h[(size_t)s4 * D + lane * 2]);
      uint_t m5 = *reinterpret_cast<const uint_t*>(&h[(size_t)s5 * D + lane * 2]);
      uint_t m6 = *reinterpret_cast<const uint_t*>(&h[(size_t)s6 * D + lane * 2]);
      uint_t m7 = *reinterpret_cast<const uint_t*>(&h[(size_t)s7 * D + lane * 2]);
      ax += bflo(m0); ay += bfhi(m0);
      ax += bflo(m1); ay += bfhi(m1);
      ax += bflo(m2); ay += bfhi(m2);
      ax += bflo(m3); ay += bfhi(m3);
      ax += bflo(m4); ay += bfhi(m4);
      ax += bflo(m5); ay += bfhi(m5);
      ax += bflo(m6); ay += bfhi(m6);
      ax += bflo(m7); ay += bfhi(m7);
    }
    for (; idx + 3 < e; idx += 4) {
      int s0 = csr[idx], s1 = csr[idx + 1], s2 = csr[idx + 2], s3 = csr[idx + 3];
      uint_t m0 = *reinterpret_cast<const uint_t*>(&h[(size_t)s0 * D + lane * 2]);
      uint_t m1 = *reinterpret_cast<const uint_t*>(&h[(size_t)s1 * D + lane * 2]);
      uint_t m2 = *reinterpret_cast<const uint_t*>(&h[(size_t)s2 * D + lane * 2]);
      uint_t m3 = *reinterpret_cast<const uint_t*>(&h[(size_t)s3 * D + lane * 2]);
      ax += bflo(m0); ay += bfhi(m0);
      ax += bflo(m1); ay += bfhi(m1);
      ax += bflo(m2); ay += bfhi(m2);
      ax += bflo(m3); ay += bfhi(m3);
    }
    for (; idx < e; idx++) {
      int s0 = csr[idx];
      uint_t m0 = *reinterpret_cast<const uint_t*>(&h[(size_t)s0 * D + lane * 2]);
      ax += bflo(m0); ay += bfhi(m0);
    }
    const float di = dinv[gid];
    float ox = ax * di + bv.x;
    float oy = ay * di + bv.y;
    if (do_elu) {
      ox = ox > 0.f ? ox : expm1f(ox);
      oy = oy > 0.f ? oy : expm1f(oy);
    }
    uint_t o = (uint_t)f2bf(ox) | ((uint_t)f2bf(oy) << 16);
    *reinterpret_cast<uint_t*>(&out[(size_t)gid * D + lane * 2]) = o;
  }
}

// ------- pooling (+ per-graph counts fused into block 0): batch sorted, run-length flush -------
__global__ __launch_bounds__(256) void pool_kernel(const ushort_t* __restrict__ h,
                                                   const int* __restrict__ batch,
                                                   float* __restrict__ pooled,
                                                   float* __restrict__ cnt, int n) {
  if (blockIdx.x == 0 && threadIdx.x < NG) {
    int g = threadIdx.x;
    int lo = 0, hi = n;
    while (lo < hi) { int mid = (lo + hi) >> 1; if (batch[mid] < g) lo = mid + 1; else hi = mid; }
    int a = lo;
    lo = 0; hi = n;
    while (lo < hi) { int mid = (lo + hi) >> 1; if (batch[mid] < g + 1) lo = mid + 1; else hi = mid; }
    cnt[g] = (float)(lo - a);
  }
  const int c  = threadIdx.x & 63;
  const int rl = threadIdx.x >> 6;
  const int base = blockIdx.x * 64;
  if (base >= n) return;
  const int end = min(base + 64, n);
  float sx = 0.f, sy = 0.f;
  int curg = -1;
  for (int i = base + rl; i < end; i += 4) {
    int g = batch[i];
    if (g != curg) {
      if (curg >= 0) {
        unsafeAtomicAdd(&pooled[curg * D + 2 * c], sx);
        unsafeAtomicAdd(&pooled[curg * D + 2 * c + 1], sy);
      }
      curg = g; sx = 0.f; sy = 0.f;
    }
    uint_t v = *reinterpret_cast<const uint_t*>(&h[(size_t)i * D + 2 * c]);
    sx += bflo(v); sy += bfhi(v);
  }
  if (curg >= 0) {
    unsafeAtomicAdd(&pooled[curg * D + 2 * c], sx);
    unsafeAtomicAdd(&pooled[curg * D + 2 * c + 1], sy);
  }
}

// ---------------- MLP head: one block per graph (f32 weights, f32 output) ----------------
__global__ __launch_bounds__(64) void mlp_kernel(const float* __restrict__ pooled,
                                                 const float* __restrict__ cnt,
                                                 const float* __restrict__ wf,
                                                 float* __restrict__ out) {
  __shared__ float g[128], h1[64], h2[32];
  const int gi = blockIdx.x, t = threadIdx.x;
  float c = fmaxf(cnt[gi], 1.0f);
  g[t] = pooled[gi * D + t] / c;
  g[t + 64] = pooled[gi * D + 64 + t] / c;
  __syncthreads();
  float a = wf[OFB1 + t];
  for (int k = 0; k < 128; k++) a += g[k] * wf[OFW1 + k * 64 + t];
  h1[t] = fmaxf(a, 0.f);
  __syncthreads();
  if (t < 32) {
    float a2 = wf[OFB2 + t];
    for (int k = 0; k < 64; k++) a2 += h1[k] * wf[OFW2 + k * 32 + t];
    h2[t] = fmaxf(a2, 0.f);
  }
  __syncthreads();
  if (t == 0) {
    float a3 = wf[OFB3];
    for (int k = 0; k < 32; k++) a3 += h2[k] * wf[OFW3 + k];
    out[gi] = a3;
  }
}

extern "C" void kernel_launch(void* const* d_in, const int* in_sizes, int n_in,
                              void* d_out, int out_size, void* d_ws, size_t ws_size,
                              hipStream_t stream) {
  (void)n_in; (void)out_size; (void)ws_size;
  const int* ei    = (const int*)d_in[13];
  const int* batch = (const int*)d_in[14];
  const int N = in_sizes[14];
  const int E = in_sizes[13] / 2;
  const int octSize = (N + 7) / 8;

  char* ws = (char*)d_ws;
  size_t off = 0;
  auto take = [&](size_t bytes) -> char* {
    char* p = ws + off;
    off += (bytes + 255) & ~(size_t)255;
    return p;
  };
  int*     flag   = (int*)take(4);
  int*     deg    = (int*)take((size_t)N * 4);
  float*   dinv   = (float*)take((size_t)N * 4);
  int*     row    = (int*)take((size_t)(N + 1) * 4);
  int*     cur    = (int*)take((size_t)N * 4);
  int*     csr    = (int*)take((size_t)E * 4);
  float*   wconv  = (float*)take((size_t)WTOT * 4);
  ushort_t* wt    = (ushort_t*)take((size_t)WT_ELEMS * 2);
  int*     bsum   = (int*)take(1024 * 4);
  ushort_t* bufA  = (ushort_t*)take((size_t)N * D * 2);
  ushort_t* bufB  = (ushort_t*)take((size_t)N * D * 2);
  float*   pooled = (float*)take((size_t)NG * D * 4);
  float*   cnt    = (float*)take((size_t)NG * 4);

  hipMemsetAsync(deg, 0, (size_t)N * 4, stream);
  hipMemsetAsync(pooled, 0, (size_t)NG * D * 4, stream);

  const int pgrid = (WTOT + WT_ELEMS + 255) / 256;
  params_kernel<<<pgrid, 256, 0, stream>>>(
      (const ushort_t*)d_in[0], d_in[1], d_in[2], d_in[3], d_in[4], d_in[5], d_in[6],
      d_in[7], d_in[8], d_in[9], d_in[10], d_in[11], d_in[12], flag, wconv, wt);

  deg_kernel<<<FILL_CHUNKS * 8, 256, 0, stream>>>(ei, deg, E, octSize);

  const int nbScan = (N + SCAN_TILE - 1) / SCAN_TILE;
  scan_phase1<<<nbScan, SCAN_BLOCK, 0, stream>>>(deg, dinv, bsum, N);
  scan_phase3<<<nbScan, SCAN_BLOCK, 0, stream>>>(deg, bsum, row, cur, N, nbScan);

  fill_kernel<<<FILL_CHUNKS * 8, 256, 0, stream>>>(ei, cur, csr, E, octSize);

  const int gemm_grid = (N + 63) / 64;
  const int agg_grid = 2048;

  gemm128_mfma<<<gemm_grid, 256, 0, stream>>>(d_in[0], wt, dinv, bufA, N, flag, 1);
  aggregate<<<agg_grid, 256, 0, stream>>>(bufA, row, csr, dinv, wconv + OB1, bufB, N, 1);
  gemm128_mfma<<<gemm_grid, 256, 0, stream>>>((const void*)bufB, wt + 16384, dinv, bufA, N, flag, 0);
  aggregate<<<agg_grid, 256, 0, stream>>>(bufA, row, csr, dinv, wconv + OB2, bufB, N, 1);
  gemm128_mfma<<<gemm_grid, 256, 0, stream>>>((const void*)bufB, wt + 32768, dinv, bufA, N, flag, 0);
  aggregate<<<agg_grid, 256, 0, stream>>>(bufA, row, csr, dinv, wconv + OB3, bufB, N, 0);

  pool_kernel<<<(N + 63) / 64, 256, 0, stream>>>(bufB, batch, pooled, cnt, N);
  mlp_kernel<<<NG, 64, 0, stream>>>(pooled, cnt, wconv, (float*)d_out);
}